// Round 2
// baseline (3401.318 us; speedup 1.0000x reference)
//
#include <hip/hip_runtime.h>
#include <hip/hip_bf16.h>

#define N_NODES 50000
#define N_EDGES 800000
#define DIM 64
#define HID 128
#define NGRAPH 128
#define BN_EPS 1e-5f

typedef __attribute__((ext_vector_type(8))) short short8;
typedef __attribute__((ext_vector_type(4))) short short4v;
typedef __attribute__((ext_vector_type(4))) float f32x4;
typedef __attribute__((ext_vector_type(4))) int int4v;

__device__ __forceinline__ float sp_(float v) {
    return fmaxf(v, 0.f) + log1pf(expf(-fabsf(v)));
}
__device__ __forceinline__ short bfb(float f) {
    __hip_bfloat16 h = __float2bfloat16(f);
    return __builtin_bit_cast(short, h);
}

// ---------------------------------------------------------------- embed
__global__ void k_embed(const int* __restrict__ az, const float* __restrict__ emb,
                        float* __restrict__ x, __hip_bfloat16* __restrict__ xb) {
    int idx = blockIdx.x * 256 + threadIdx.x;
    if (idx >= N_NODES * DIM) return;
    int n = idx >> 6;
    int d = idx & 63;
    float v = emb[az[n] * DIM + d];
    x[idx] = v;
    xb[idx] = __float2bfloat16(v);
}

// ---------------------------------------------------------------- edge MLP
// tile = 64 edges, 4 waves, N=128 cols (32/wave), K=128 (+rank-1 attr term)
__launch_bounds__(256, 1)
__global__ void k_edge(const __hip_bfloat16* __restrict__ xb,
                       const int* __restrict__ esrc, const int* __restrict__ edst,
                       const float* __restrict__ eattr,
                       const float* __restrict__ W1, const float* __restrict__ b1,
                       const float* __restrict__ W2, const float* __restrict__ b2,
                       float* __restrict__ aggr) {
    __shared__ short w1t[128 * 128];   // [n][k] swizzled, 32KB
    __shared__ short w2t[128 * 128];   // 32KB
    __shared__ short zt[64 * 128];     // 16KB
    __shared__ short ht[64 * 128];     // 16KB
    __shared__ float attr_s[64];
    __shared__ int   dst_s[64];
    __shared__ float w1last[128], b1s[128], b2s[128];

    const int t = threadIdx.x;
    // stage weights (transposed into [n][k], swizzled)
    for (int idx = t; idx < 128 * 128; idx += 256) {
        int k = idx >> 7, n = idx & 127;
        *(short*)((char*)w1t + n * 256 + ((k * 2) ^ ((n & 7) << 4))) = bfb(W1[k * 128 + n]);
        *(short*)((char*)w2t + n * 256 + ((k * 2) ^ ((n & 7) << 4))) = bfb(W2[k * 128 + n]);
    }
    if (t < 128) {
        w1last[t] = W1[128 * 128 + t];
        b1s[t] = b1[t];
        b2s[t] = b2[t];
    }
    __syncthreads();

    const int wid = t >> 6, lane = t & 63;
    const int lrow = lane & 15, lk = lane >> 4;
    const int r = t >> 2, q = t & 3;
    const int nc0 = wid * 32;

    for (int tile = blockIdx.x; tile < N_EDGES / 64; tile += gridDim.x) {
        const int e0 = tile * 64;
        // ---- stage z tile: cols 0..63 = x[dst], 64..127 = x[src]
        {
            int e = e0 + r;
            int dn = edst[e], sn = esrc[e];
            if (q == 0) { dst_s[r] = dn; attr_s[r] = eattr[e]; }
            const __hip_bfloat16* xr = xb + (size_t)(q < 2 ? dn : sn) * DIM + (q & 1) * 32;
#pragma unroll
            for (int i = 0; i < 4; i++) {
                int4v v = *(const int4v*)(xr + i * 8);
                int cb = q * 64 + i * 16;
                *(int4v*)((char*)zt + r * 256 + (cb ^ ((r & 7) << 4))) = v;
            }
        }
        __syncthreads();

        // ---- GEMM1: [64x128] @ [128x128]
        f32x4 acc[4][2];
#pragma unroll
        for (int mi = 0; mi < 4; mi++)
#pragma unroll
            for (int ni = 0; ni < 2; ni++) acc[mi][ni] = (f32x4){0.f, 0.f, 0.f, 0.f};
#pragma unroll
        for (int ks = 0; ks < 4; ks++) {
            int kb = ks * 64 + lk * 16;
            short8 av[4], bv[2];
#pragma unroll
            for (int mi = 0; mi < 4; mi++) {
                int row = mi * 16 + lrow;
                av[mi] = *(const short8*)((const char*)zt + row * 256 + (kb ^ ((row & 7) << 4)));
            }
#pragma unroll
            for (int ni = 0; ni < 2; ni++) {
                int col = nc0 + ni * 16 + lrow;
                bv[ni] = *(const short8*)((const char*)w1t + col * 256 + (kb ^ ((col & 7) << 4)));
            }
#pragma unroll
            for (int mi = 0; mi < 4; mi++)
#pragma unroll
                for (int ni = 0; ni < 2; ni++)
                    acc[mi][ni] = __builtin_amdgcn_mfma_f32_16x16x32_bf16(av[mi], bv[ni], acc[mi][ni], 0, 0, 0);
        }
        // epilogue 1: + b1 + attr * W1_lastrow, softplus, -> ht (bf16)
#pragma unroll
        for (int mi = 0; mi < 4; mi++) {
#pragma unroll
            for (int ni = 0; ni < 2; ni++) {
                int col = nc0 + ni * 16 + lrow;
                float wl = w1last[col], bb = b1s[col];
#pragma unroll
                for (int rr = 0; rr < 4; rr++) {
                    int row = mi * 16 + lk * 4 + rr;
                    float val = acc[mi][ni][rr] + bb + attr_s[row] * wl;
                    *(short*)((char*)ht + row * 256 + ((col * 2) ^ ((row & 7) << 4))) = bfb(sp_(val));
                }
            }
        }
        __syncthreads();

        // ---- GEMM2: [64x128] @ [128x128]
        f32x4 acc2[4][2];
#pragma unroll
        for (int mi = 0; mi < 4; mi++)
#pragma unroll
            for (int ni = 0; ni < 2; ni++) acc2[mi][ni] = (f32x4){0.f, 0.f, 0.f, 0.f};
#pragma unroll
        for (int ks = 0; ks < 4; ks++) {
            int kb = ks * 64 + lk * 16;
            short8 av[4], bv[2];
#pragma unroll
            for (int mi = 0; mi < 4; mi++) {
                int row = mi * 16 + lrow;
                av[mi] = *(const short8*)((const char*)ht + row * 256 + (kb ^ ((row & 7) << 4)));
            }
#pragma unroll
            for (int ni = 0; ni < 2; ni++) {
                int col = nc0 + ni * 16 + lrow;
                bv[ni] = *(const short8*)((const char*)w2t + col * 256 + (kb ^ ((col & 7) << 4)));
            }
#pragma unroll
            for (int mi = 0; mi < 4; mi++)
#pragma unroll
                for (int ni = 0; ni < 2; ni++)
                    acc2[mi][ni] = __builtin_amdgcn_mfma_f32_16x16x32_bf16(av[mi], bv[ni], acc2[mi][ni], 0, 0, 0);
        }
        // epilogue 2: softplus(+b2), atomic scatter-add into aggr[dst]
#pragma unroll
        for (int mi = 0; mi < 4; mi++) {
#pragma unroll
            for (int ni = 0; ni < 2; ni++) {
                int col = nc0 + ni * 16 + lrow;
                float bb = b2s[col];
#pragma unroll
                for (int rr = 0; rr < 4; rr++) {
                    int row = mi * 16 + lk * 4 + rr;
                    float val = sp_(acc2[mi][ni][rr] + bb);
                    atomicAdd(&aggr[(size_t)dst_s[row] * HID + col], val);
                }
            }
        }
        __syncthreads();
    }
}

// ---------------------------------------------------------------- node MLP + BN partial stats
// tile = 64 nodes, K=192 (x||aggr) -> H=128 -> sp -> K=128 -> D=64, +x residual
__launch_bounds__(256, 1)
__global__ void k_node(const __hip_bfloat16* __restrict__ xb,
                       const float* __restrict__ xf,
                       const float* __restrict__ aggr,
                       const float* __restrict__ W1, const float* __restrict__ b1,
                       const float* __restrict__ W2, const float* __restrict__ b2,
                       float* __restrict__ y, float* __restrict__ stats) {
    __shared__ short at[64 * 192];    // 24KB rowbytes 384
    __shared__ short w1t[128 * 192];  // 48KB [n][k]
    __shared__ short ht[64 * 128];    // 16KB
    __shared__ short w2t[64 * 128];   // 16KB [n][k]
    __shared__ float b1s[128], b2s[64];

    const int t = threadIdx.x;
    for (int idx = t; idx < 192 * 128; idx += 256) {
        int k = idx >> 7, n = idx & 127;
        *(short*)((char*)w1t + n * 384 + ((k * 2) ^ ((n & 7) << 4))) = bfb(W1[idx]);
    }
    for (int idx = t; idx < 128 * 64; idx += 256) {
        int k = idx >> 6, n = idx & 63;
        *(short*)((char*)w2t + n * 256 + ((k * 2) ^ ((n & 7) << 4))) = bfb(W2[idx]);
    }
    if (t < 128) b1s[t] = b1[t];
    if (t < 64) b2s[t] = b2[t];
    __syncthreads();

    const int wid = t >> 6, lane = t & 63, lrow = lane & 15, lk = lane >> 4;
    const int n0 = blockIdx.x * 64;

    // stage A rows: [x bf16 (64) || aggr f32->bf16 (128)]
    if (t < 64) {
        int node = n0 + t;
        if (node < N_NODES) {
            const __hip_bfloat16* xr = xb + (size_t)node * DIM;
#pragma unroll
            for (int i = 0; i < 8; i++) {
                int4v v = *(const int4v*)(xr + i * 8);
                *(int4v*)((char*)at + t * 384 + ((i * 16) ^ ((t & 7) << 4))) = v;
            }
        } else {
            int4v z = {0, 0, 0, 0};
#pragma unroll
            for (int i = 0; i < 8; i++)
                *(int4v*)((char*)at + t * 384 + ((i * 16) ^ ((t & 7) << 4))) = z;
        }
    }
    {
        int r = t >> 2, q = t & 3;
        int node = n0 + r;
#pragma unroll
        for (int i = 0; i < 4; i++) {
            short8 s = {0, 0, 0, 0, 0, 0, 0, 0};
            if (node < N_NODES) {
                const float* ar = aggr + (size_t)node * HID + q * 32 + i * 8;
                float4 f0 = *(const float4*)ar;
                float4 f1 = *(const float4*)(ar + 4);
                s = (short8){bfb(f0.x), bfb(f0.y), bfb(f0.z), bfb(f0.w),
                             bfb(f1.x), bfb(f1.y), bfb(f1.z), bfb(f1.w)};
            }
            int cb = 128 + q * 64 + i * 16;
            *(short8*)((char*)at + r * 384 + (cb ^ ((r & 7) << 4))) = s;
        }
    }
    __syncthreads();

    // GEMM1: [64x192] @ [192x128]
    f32x4 acc[4][2];
#pragma unroll
    for (int mi = 0; mi < 4; mi++)
#pragma unroll
        for (int ni = 0; ni < 2; ni++) acc[mi][ni] = (f32x4){0.f, 0.f, 0.f, 0.f};
    const int nc0 = wid * 32;
#pragma unroll
    for (int ks = 0; ks < 6; ks++) {
        int kb = ks * 64 + lk * 16;
        short8 av[4], bv[2];
#pragma unroll
        for (int mi = 0; mi < 4; mi++) {
            int row = mi * 16 + lrow;
            av[mi] = *(const short8*)((const char*)at + row * 384 + (kb ^ ((row & 7) << 4)));
        }
#pragma unroll
        for (int ni = 0; ni < 2; ni++) {
            int col = nc0 + ni * 16 + lrow;
            bv[ni] = *(const short8*)((const char*)w1t + col * 384 + (kb ^ ((col & 7) << 4)));
        }
#pragma unroll
        for (int mi = 0; mi < 4; mi++)
#pragma unroll
            for (int ni = 0; ni < 2; ni++)
                acc[mi][ni] = __builtin_amdgcn_mfma_f32_16x16x32_bf16(av[mi], bv[ni], acc[mi][ni], 0, 0, 0);
    }
#pragma unroll
    for (int mi = 0; mi < 4; mi++) {
#pragma unroll
        for (int ni = 0; ni < 2; ni++) {
            int col = nc0 + ni * 16 + lrow;
            float bb = b1s[col];
#pragma unroll
            for (int rr = 0; rr < 4; rr++) {
                int row = mi * 16 + lk * 4 + rr;
                float val = sp_(acc[mi][ni][rr] + bb);
                *(short*)((char*)ht + row * 256 + ((col * 2) ^ ((row & 7) << 4))) = bfb(val);
            }
        }
    }
    __syncthreads();

    // GEMM2: [64x128] @ [128x64], each wave owns 16 output cols
    f32x4 acc2[4];
#pragma unroll
    for (int mi = 0; mi < 4; mi++) acc2[mi] = (f32x4){0.f, 0.f, 0.f, 0.f};
    const int nc2 = wid * 16;
#pragma unroll
    for (int ks = 0; ks < 4; ks++) {
        int kb = ks * 64 + lk * 16;
        short8 av[4];
#pragma unroll
        for (int mi = 0; mi < 4; mi++) {
            int row = mi * 16 + lrow;
            av[mi] = *(const short8*)((const char*)ht + row * 256 + (kb ^ ((row & 7) << 4)));
        }
        int col = nc2 + lrow;
        short8 bv = *(const short8*)((const char*)w2t + col * 256 + (kb ^ ((col & 7) << 4)));
#pragma unroll
        for (int mi = 0; mi < 4; mi++)
            acc2[mi] = __builtin_amdgcn_mfma_f32_16x16x32_bf16(av[mi], bv, acc2[mi], 0, 0, 0);
    }
    // epilogue: +b2 +x residual, write y, BN partial sums
    float s1 = 0.f, s2 = 0.f;
    const int col = nc2 + lrow;
    const float bb = b2s[col];
#pragma unroll
    for (int mi = 0; mi < 4; mi++) {
#pragma unroll
        for (int rr = 0; rr < 4; rr++) {
            int row = mi * 16 + lk * 4 + rr;
            int node = n0 + row;
            if (node < N_NODES) {
                float v = acc2[mi][rr] + bb + xf[(size_t)node * DIM + col];
                y[(size_t)node * DIM + col] = v;
                s1 += v;
                s2 += v * v;
            }
        }
    }
    s1 += __shfl_xor(s1, 16); s1 += __shfl_xor(s1, 32);
    s2 += __shfl_xor(s2, 16); s2 += __shfl_xor(s2, 32);
    if (lane < 16) {
        atomicAdd(&stats[col], s1);
        atomicAdd(&stats[64 + col], s2);
    }
}

// ---------------------------------------------------------------- BN finalize: a=gamma*rstd, b=beta-mu*a
__global__ void k_bnfin(const float* __restrict__ gamma, const float* __restrict__ beta,
                        float* __restrict__ stats) {
    int d = threadIdx.x;
    float mu = stats[d] * (1.f / N_NODES);
    float var = stats[64 + d] * (1.f / N_NODES) - mu * mu;
    float rstd = rsqrtf(var + BN_EPS);
    float a = gamma[d] * rstd;
    stats[128 + d] = a;
    stats[192 + d] = beta[d] - mu * a;
}

// ---------------------------------------------------------------- BN apply -> new x (f32 + bf16)
__global__ void k_bnapply(const float* __restrict__ y, const float* __restrict__ stats,
                          float* __restrict__ x, __hip_bfloat16* __restrict__ xb) {
    int idx = (blockIdx.x * 256 + threadIdx.x) * 4;
    if (idx >= N_NODES * DIM) return;
    int d = idx & 63;
    float4 v = *(const float4*)(y + idx);
    float4 r;
    r.x = stats[128 + d + 0] * v.x + stats[192 + d + 0];
    r.y = stats[128 + d + 1] * v.y + stats[192 + d + 1];
    r.z = stats[128 + d + 2] * v.z + stats[192 + d + 2];
    r.w = stats[128 + d + 3] * v.w + stats[192 + d + 3];
    *(float4*)(x + idx) = r;
    short4v s = {bfb(r.x), bfb(r.y), bfb(r.z), bfb(r.w)};
    *(short4v*)((char*)(xb + idx)) = s;
}

// ---------------------------------------------------------------- pool (atomic mean prep)
__global__ void k_pool(const int* __restrict__ batch, const float* __restrict__ x,
                       float* __restrict__ psum, float* __restrict__ pcnt) {
    int t = threadIdx.x;
    int nloc = t >> 6, d = t & 63;
    int node = blockIdx.x * 4 + nloc;
    if (node >= N_NODES) return;
    int g = batch[node];
    atomicAdd(&psum[g * 64 + d], x[(size_t)node * 64 + d]);
    if (d == 0) atomicAdd(&pcnt[g], 1.f);
}

// ---------------------------------------------------------------- output MLP (f32)
__global__ void k_out(const float* __restrict__ psum, const float* __restrict__ pcnt,
                      const float* __restrict__ W1, const float* __restrict__ b1,
                      const float* __restrict__ W2, const float* __restrict__ b2,
                      float* __restrict__ out) {
    __shared__ float pl[64];
    __shared__ float wsum[2];
    int g = blockIdx.x, t = threadIdx.x;
    if (t < 64) pl[t] = psum[g * 64 + t] / fmaxf(pcnt[g], 1.f);
    __syncthreads();
    float a = b1[t];
#pragma unroll
    for (int d = 0; d < 64; d++) a += pl[d] * W1[d * 128 + t];
    float c = sp_(a) * W2[t];
#pragma unroll
    for (int off = 32; off >= 1; off >>= 1) c += __shfl_down(c, off);
    int lane = t & 63, wid = t >> 6;
    if (lane == 0) wsum[wid] = c;
    __syncthreads();
    if (t == 0) out[g] = wsum[0] + wsum[1] + b2[0];
}

// ---------------------------------------------------------------- launch
extern "C" void kernel_launch(void* const* d_in, const int* in_sizes, int n_in,
                              void* d_out, int out_size, void* d_ws, size_t ws_size,
                              hipStream_t stream) {
    const int*   az    = (const int*)d_in[0];
    const int*   ei    = (const int*)d_in[1];
    const float* eattr = (const float*)d_in[2];
    const int*   batch = (const int*)d_in[3];
    const float* emb   = (const float*)d_in[4];
    const float* eW1   = (const float*)d_in[5];
    const float* eb1   = (const float*)d_in[6];
    const float* eW2   = (const float*)d_in[7];
    const float* eb2   = (const float*)d_in[8];
    const float* nW1   = (const float*)d_in[9];
    const float* nb1   = (const float*)d_in[10];
    const float* nW2   = (const float*)d_in[11];
    const float* nb2   = (const float*)d_in[12];
    const float* gam   = (const float*)d_in[13];
    const float* bet   = (const float*)d_in[14];
    const float* oW1   = (const float*)d_in[15];
    const float* ob1   = (const float*)d_in[16];
    const float* oW2   = (const float*)d_in[17];
    const float* ob2   = (const float*)d_in[18];
    const int* esrc = ei;
    const int* edst = ei + N_EDGES;

    float* x     = (float*)d_ws;
    float* y     = x + (size_t)N_NODES * DIM;
    float* aggr  = y + (size_t)N_NODES * DIM;
    float* stats = aggr + (size_t)N_NODES * HID;
    float* psum  = stats + 256;
    float* pcnt  = psum + NGRAPH * 64;
    __hip_bfloat16* xb = (__hip_bfloat16*)(pcnt + NGRAPH);

    k_embed<<<(N_NODES * DIM + 255) / 256, 256, 0, stream>>>(az, emb, x, xb);

    for (int l = 0; l < 3; l++) {
        hipMemsetAsync(aggr, 0, (size_t)N_NODES * HID * sizeof(float), stream);
        hipMemsetAsync(stats, 0, 256 * sizeof(float), stream);
        k_edge<<<2048, 256, 0, stream>>>(xb, esrc, edst, eattr,
                                         eW1 + (size_t)l * 129 * 128, eb1 + l * 128,
                                         eW2 + (size_t)l * 128 * 128, eb2 + l * 128, aggr);
        k_node<<<(N_NODES + 63) / 64, 256, 0, stream>>>(xb, x, aggr,
                                                        nW1 + (size_t)l * 192 * 128, nb1 + l * 128,
                                                        nW2 + (size_t)l * 128 * 64, nb2 + l * 64,
                                                        y, stats);
        k_bnfin<<<1, 64, 0, stream>>>(gam + l * 64, bet + l * 64, stats);
        k_bnapply<<<(N_NODES * DIM / 4 + 255) / 256, 256, 0, stream>>>(y, stats, x, xb);
    }

    hipMemsetAsync(psum, 0, (NGRAPH * 64 + NGRAPH) * sizeof(float), stream);
    k_pool<<<(N_NODES + 3) / 4, 256, 0, stream>>>(batch, x, psum, pcnt);
    k_out<<<NGRAPH, 128, 0, stream>>>(psum, pcnt, oW1, ob1, oW2, ob2, (float*)d_out);
}

// Round 3
// 1560.322 us; speedup vs baseline: 2.1799x; 2.1799x over previous
//
#include <hip/hip_runtime.h>
#include <hip/hip_bf16.h>

#define N_NODES 50000
#define N_EDGES 800000
#define DIM 64
#define HID 128
#define NGRAPH 128
#define BN_EPS 1e-5f

typedef __attribute__((ext_vector_type(8))) short short8;
typedef __attribute__((ext_vector_type(4))) short short4v;
typedef __attribute__((ext_vector_type(4))) float f32x4;
typedef __attribute__((ext_vector_type(4))) int int4v;

__device__ __forceinline__ float sp_(float v) {
    // softplus via hardware v_exp_f32 / v_log_f32 (~1e-6 abs err, fine at bf16)
    return fmaxf(v, 0.f) + __logf(1.f + __expf(-fabsf(v)));
}
__device__ __forceinline__ short bfb(float f) {
    __hip_bfloat16 h = __float2bfloat16(f);
    return __builtin_bit_cast(short, h);
}

// ---------------------------------------------------------------- embed
__global__ void k_embed(const int* __restrict__ az, const float* __restrict__ emb,
                        float* __restrict__ x, __hip_bfloat16* __restrict__ xb) {
    int idx = blockIdx.x * 256 + threadIdx.x;
    if (idx >= N_NODES * DIM) return;
    int n = idx >> 6;
    int d = idx & 63;
    float v = emb[az[n] * DIM + d];
    x[idx] = v;
    xb[idx] = __float2bfloat16(v);
}

// ---------------------------------------------------------------- weight prep:
// transpose f32 [K][N] (row-major) -> bf16 [N][K]; blockIdx.y = layer
__global__ void k_wprep(const float* __restrict__ src, short* __restrict__ dst,
                        int total, int nshift, int srcStride) {
    int l = blockIdx.y;
    int idx = blockIdx.x * 256 + threadIdx.x;
    if (idx >= total) return;
    int K = total >> nshift;
    int k = idx >> nshift;
    int n = idx & ((1 << nshift) - 1);
    dst[(size_t)l * total + n * K + k] = bfb(src[(size_t)l * srcStride + idx]);
}

// ---------------------------------------------------------------- edge MLP
// tile = 64 edges, 4 waves, N=128 cols (32/wave), K=128 (+rank-1 attr term)
// weights live in registers (pre-transposed bf16), LDS only for z/h tiles
__launch_bounds__(256, 2)
__global__ void k_edge(const __hip_bfloat16* __restrict__ xb,
                       const int* __restrict__ esrc, const int* __restrict__ edst,
                       const float* __restrict__ eattr,
                       const float* __restrict__ W1f, const float* __restrict__ b1,
                       const float* __restrict__ b2,
                       const short* __restrict__ w1T, const short* __restrict__ w2T,
                       float* __restrict__ aggr) {
    __shared__ short zt[64 * 128];     // 16KB
    __shared__ short ht[64 * 128];     // 16KB
    __shared__ float attr_s[64];
    __shared__ int   dstoff_s[64];

    const int t = threadIdx.x;
    const int wid = t >> 6, lane = t & 63;
    const int lrow = lane & 15, lk = lane >> 4;
    const int r = t >> 2, q = t & 3;
    const int nc0 = wid * 32;

    // preload weight fragments + per-col scalars into registers
    short8 w1f[4][2], w2f[4][2];
    float b1v[2], b2v[2], wlv[2];
#pragma unroll
    for (int ni = 0; ni < 2; ni++) {
        int col = nc0 + ni * 16 + lrow;
#pragma unroll
        for (int ks = 0; ks < 4; ks++) {
            int kb = ks * 64 + lk * 16;
            w1f[ks][ni] = *(const short8*)((const char*)w1T + col * 256 + kb);
            w2f[ks][ni] = *(const short8*)((const char*)w2T + col * 256 + kb);
        }
        b1v[ni] = b1[col];
        b2v[ni] = b2[col];
        wlv[ni] = W1f[128 * 128 + col];   // attr rank-1 row (f32 original)
    }

    for (int tile = blockIdx.x; tile < N_EDGES / 64; tile += gridDim.x) {
        const int e0 = tile * 64;
        // ---- stage z tile: cols 0..63 = x[dst], 64..127 = x[src]
        {
            int e = e0 + r;
            int dn = edst[e], sn = esrc[e];
            if (q == 0) { dstoff_s[r] = dn * HID; attr_s[r] = eattr[e]; }
            const __hip_bfloat16* xr = xb + (size_t)(q < 2 ? dn : sn) * DIM + (q & 1) * 32;
#pragma unroll
            for (int i = 0; i < 4; i++) {
                int4v v = *(const int4v*)(xr + i * 8);
                int cb = q * 64 + i * 16;
                *(int4v*)((char*)zt + r * 256 + (cb ^ ((r & 7) << 4))) = v;
            }
        }
        __syncthreads();

        // ---- GEMM1: [64x128] @ [128x128]
        f32x4 acc[4][2];
#pragma unroll
        for (int mi = 0; mi < 4; mi++)
#pragma unroll
            for (int ni = 0; ni < 2; ni++) acc[mi][ni] = (f32x4){0.f, 0.f, 0.f, 0.f};
#pragma unroll
        for (int ks = 0; ks < 4; ks++) {
            int kb = ks * 64 + lk * 16;
            short8 av[4];
#pragma unroll
            for (int mi = 0; mi < 4; mi++) {
                int row = mi * 16 + lrow;
                av[mi] = *(const short8*)((const char*)zt + row * 256 + (kb ^ ((row & 7) << 4)));
            }
#pragma unroll
            for (int mi = 0; mi < 4; mi++)
#pragma unroll
                for (int ni = 0; ni < 2; ni++)
                    acc[mi][ni] = __builtin_amdgcn_mfma_f32_16x16x32_bf16(av[mi], w1f[ks][ni], acc[mi][ni], 0, 0, 0);
        }
        // epilogue 1: + b1 + attr * W1_lastrow, softplus, -> ht (bf16)
#pragma unroll
        for (int mi = 0; mi < 4; mi++) {
#pragma unroll
            for (int ni = 0; ni < 2; ni++) {
                int col = nc0 + ni * 16 + lrow;
#pragma unroll
                for (int rr = 0; rr < 4; rr++) {
                    int row = mi * 16 + lk * 4 + rr;
                    float val = acc[mi][ni][rr] + b1v[ni] + attr_s[row] * wlv[ni];
                    *(short*)((char*)ht + row * 256 + ((col * 2) ^ ((row & 7) << 4))) = bfb(sp_(val));
                }
            }
        }
        __syncthreads();

        // ---- GEMM2: [64x128] @ [128x128]
        f32x4 acc2[4][2];
#pragma unroll
        for (int mi = 0; mi < 4; mi++)
#pragma unroll
            for (int ni = 0; ni < 2; ni++) acc2[mi][ni] = (f32x4){0.f, 0.f, 0.f, 0.f};
#pragma unroll
        for (int ks = 0; ks < 4; ks++) {
            int kb = ks * 64 + lk * 16;
            short8 av[4];
#pragma unroll
            for (int mi = 0; mi < 4; mi++) {
                int row = mi * 16 + lrow;
                av[mi] = *(const short8*)((const char*)ht + row * 256 + (kb ^ ((row & 7) << 4)));
            }
#pragma unroll
            for (int mi = 0; mi < 4; mi++)
#pragma unroll
                for (int ni = 0; ni < 2; ni++)
                    acc2[mi][ni] = __builtin_amdgcn_mfma_f32_16x16x32_bf16(av[mi], w2f[ks][ni], acc2[mi][ni], 0, 0, 0);
        }
        // epilogue 2: softplus(+b2), atomic scatter-add into aggr[dst]
#pragma unroll
        for (int mi = 0; mi < 4; mi++) {
#pragma unroll
            for (int ni = 0; ni < 2; ni++) {
                int col = nc0 + ni * 16 + lrow;
#pragma unroll
                for (int rr = 0; rr < 4; rr++) {
                    int row = mi * 16 + lk * 4 + rr;
                    float val = sp_(acc2[mi][ni][rr] + b2v[ni]);
                    atomicAdd(&aggr[dstoff_s[row] + col], val);
                }
            }
        }
        __syncthreads();
    }
}

// ---------------------------------------------------------------- node MLP + BN partial stats
// tile = 64 nodes, K=192 (x||aggr) -> H=128 -> sp -> K=128 -> D=64, +x residual
__launch_bounds__(256, 2)
__global__ void k_node(const __hip_bfloat16* __restrict__ xb,
                       const float* __restrict__ xf,
                       const float* __restrict__ aggr,
                       const short* __restrict__ w1T, const float* __restrict__ b1,
                       const short* __restrict__ w2T, const float* __restrict__ b2,
                       float* __restrict__ y, float* __restrict__ stats) {
    __shared__ short at[64 * 192];    // 24KB rowbytes 384
    __shared__ short ht[64 * 128];    // 16KB

    const int t = threadIdx.x;
    const int wid = t >> 6, lane = t & 63, lrow = lane & 15, lk = lane >> 4;
    const int n0 = blockIdx.x * 64;

    // preload weight fragments
    const int nc0 = wid * 32;
    short8 w1f[6][2];
    float b1v[2];
#pragma unroll
    for (int ni = 0; ni < 2; ni++) {
        int col = nc0 + ni * 16 + lrow;
#pragma unroll
        for (int ks = 0; ks < 6; ks++) {
            int kb = ks * 64 + lk * 16;
            w1f[ks][ni] = *(const short8*)((const char*)w1T + col * 384 + kb);
        }
        b1v[ni] = b1[col];
    }
    const int nc2 = wid * 16;
    const int col2 = nc2 + lrow;
    short8 w2f[4];
#pragma unroll
    for (int ks = 0; ks < 4; ks++)
        w2f[ks] = *(const short8*)((const char*)w2T + col2 * 256 + ks * 64 + lk * 16);
    const float b2v = b2[col2];

    // stage A rows: [x bf16 (64) || aggr f32->bf16 (128)]
    if (t < 64) {
        int node = n0 + t;
        if (node < N_NODES) {
            const __hip_bfloat16* xr = xb + (size_t)node * DIM;
#pragma unroll
            for (int i = 0; i < 8; i++) {
                int4v v = *(const int4v*)(xr + i * 8);
                *(int4v*)((char*)at + t * 384 + ((i * 16) ^ ((t & 7) << 4))) = v;
            }
        } else {
            int4v z = {0, 0, 0, 0};
#pragma unroll
            for (int i = 0; i < 8; i++)
                *(int4v*)((char*)at + t * 384 + ((i * 16) ^ ((t & 7) << 4))) = z;
        }
    }
    {
        int r = t >> 2, q = t & 3;
        int node = n0 + r;
#pragma unroll
        for (int i = 0; i < 4; i++) {
            short8 s = {0, 0, 0, 0, 0, 0, 0, 0};
            if (node < N_NODES) {
                const float* ar = aggr + (size_t)node * HID + q * 32 + i * 8;
                float4 f0 = *(const float4*)ar;
                float4 f1 = *(const float4*)(ar + 4);
                s = (short8){bfb(f0.x), bfb(f0.y), bfb(f0.z), bfb(f0.w),
                             bfb(f1.x), bfb(f1.y), bfb(f1.z), bfb(f1.w)};
            }
            int cb = 128 + q * 64 + i * 16;
            *(short8*)((char*)at + r * 384 + (cb ^ ((r & 7) << 4))) = s;
        }
    }
    __syncthreads();

    // GEMM1: [64x192] @ [192x128]
    f32x4 acc[4][2];
#pragma unroll
    for (int mi = 0; mi < 4; mi++)
#pragma unroll
        for (int ni = 0; ni < 2; ni++) acc[mi][ni] = (f32x4){0.f, 0.f, 0.f, 0.f};
#pragma unroll
    for (int ks = 0; ks < 6; ks++) {
        int kb = ks * 64 + lk * 16;
        short8 av[4];
#pragma unroll
        for (int mi = 0; mi < 4; mi++) {
            int row = mi * 16 + lrow;
            av[mi] = *(const short8*)((const char*)at + row * 384 + (kb ^ ((row & 7) << 4)));
        }
#pragma unroll
        for (int mi = 0; mi < 4; mi++)
#pragma unroll
            for (int ni = 0; ni < 2; ni++)
                acc[mi][ni] = __builtin_amdgcn_mfma_f32_16x16x32_bf16(av[mi], w1f[ks][ni], acc[mi][ni], 0, 0, 0);
    }
#pragma unroll
    for (int mi = 0; mi < 4; mi++) {
#pragma unroll
        for (int ni = 0; ni < 2; ni++) {
            int col = nc0 + ni * 16 + lrow;
#pragma unroll
            for (int rr = 0; rr < 4; rr++) {
                int row = mi * 16 + lk * 4 + rr;
                float val = sp_(acc[mi][ni][rr] + b1v[ni]);
                *(short*)((char*)ht + row * 256 + ((col * 2) ^ ((row & 7) << 4))) = bfb(val);
            }
        }
    }
    __syncthreads();

    // GEMM2: [64x128] @ [128x64], each wave owns 16 output cols
    f32x4 acc2[4];
#pragma unroll
    for (int mi = 0; mi < 4; mi++) acc2[mi] = (f32x4){0.f, 0.f, 0.f, 0.f};
#pragma unroll
    for (int ks = 0; ks < 4; ks++) {
        int kb = ks * 64 + lk * 16;
        short8 av[4];
#pragma unroll
        for (int mi = 0; mi < 4; mi++) {
            int row = mi * 16 + lrow;
            av[mi] = *(const short8*)((const char*)ht + row * 256 + (kb ^ ((row & 7) << 4)));
        }
#pragma unroll
        for (int mi = 0; mi < 4; mi++)
            acc2[mi] = __builtin_amdgcn_mfma_f32_16x16x32_bf16(av[mi], w2f[ks], acc2[mi], 0, 0, 0);
    }
    // epilogue: +b2 +x residual, write y, BN partial sums
    float s1 = 0.f, s2 = 0.f;
#pragma unroll
    for (int mi = 0; mi < 4; mi++) {
#pragma unroll
        for (int rr = 0; rr < 4; rr++) {
            int row = mi * 16 + lk * 4 + rr;
            int node = n0 + row;
            if (node < N_NODES) {
                float v = acc2[mi][rr] + b2v + xf[(size_t)node * DIM + col2];
                y[(size_t)node * DIM + col2] = v;
                s1 += v;
                s2 += v * v;
            }
        }
    }
    s1 += __shfl_xor(s1, 16); s1 += __shfl_xor(s1, 32);
    s2 += __shfl_xor(s2, 16); s2 += __shfl_xor(s2, 32);
    if (lane < 16) {
        atomicAdd(&stats[col2], s1);
        atomicAdd(&stats[64 + col2], s2);
    }
}

// ---------------------------------------------------------------- BN finalize: a=gamma*rstd, b=beta-mu*a
__global__ void k_bnfin(const float* __restrict__ gamma, const float* __restrict__ beta,
                        float* __restrict__ stats) {
    int d = threadIdx.x;
    float mu = stats[d] * (1.f / N_NODES);
    float var = stats[64 + d] * (1.f / N_NODES) - mu * mu;
    float rstd = rsqrtf(var + BN_EPS);
    float a = gamma[d] * rstd;
    stats[128 + d] = a;
    stats[192 + d] = beta[d] - mu * a;
}

// ---------------------------------------------------------------- BN apply -> new x (f32 + bf16)
__global__ void k_bnapply(const float* __restrict__ y, const float* __restrict__ stats,
                          float* __restrict__ x, __hip_bfloat16* __restrict__ xb) {
    int idx = (blockIdx.x * 256 + threadIdx.x) * 4;
    if (idx >= N_NODES * DIM) return;
    int d = idx & 63;
    float4 v = *(const float4*)(y + idx);
    float4 r;
    r.x = stats[128 + d + 0] * v.x + stats[192 + d + 0];
    r.y = stats[128 + d + 1] * v.y + stats[192 + d + 1];
    r.z = stats[128 + d + 2] * v.z + stats[192 + d + 2];
    r.w = stats[128 + d + 3] * v.w + stats[192 + d + 3];
    *(float4*)(x + idx) = r;
    short4v s = {bfb(r.x), bfb(r.y), bfb(r.z), bfb(r.w)};
    *(short4v*)((char*)(xb + idx)) = s;
}

// ---------------------------------------------------------------- pool (atomic mean prep)
__global__ void k_pool(const int* __restrict__ batch, const float* __restrict__ x,
                       float* __restrict__ psum, float* __restrict__ pcnt) {
    int t = threadIdx.x;
    int nloc = t >> 6, d = t & 63;
    int node = blockIdx.x * 4 + nloc;
    if (node >= N_NODES) return;
    int g = batch[node];
    atomicAdd(&psum[g * 64 + d], x[(size_t)node * 64 + d]);
    if (d == 0) atomicAdd(&pcnt[g], 1.f);
}

// ---------------------------------------------------------------- output MLP (f32)
__global__ void k_out(const float* __restrict__ psum, const float* __restrict__ pcnt,
                      const float* __restrict__ W1, const float* __restrict__ b1,
                      const float* __restrict__ W2, const float* __restrict__ b2,
                      float* __restrict__ out) {
    __shared__ float pl[64];
    __shared__ float wsum[2];
    int g = blockIdx.x, t = threadIdx.x;
    if (t < 64) pl[t] = psum[g * 64 + t] / fmaxf(pcnt[g], 1.f);
    __syncthreads();
    float a = b1[t];
#pragma unroll
    for (int d = 0; d < 64; d++) a += pl[d] * W1[d * 128 + t];
    float c = sp_(a) * W2[t];
#pragma unroll
    for (int off = 32; off >= 1; off >>= 1) c += __shfl_down(c, off);
    int lane = t & 63, wid = t >> 6;
    if (lane == 0) wsum[wid] = c;
    __syncthreads();
    if (t == 0) out[g] = wsum[0] + wsum[1] + b2[0];
}

// ---------------------------------------------------------------- launch
extern "C" void kernel_launch(void* const* d_in, const int* in_sizes, int n_in,
                              void* d_out, int out_size, void* d_ws, size_t ws_size,
                              hipStream_t stream) {
    const int*   az    = (const int*)d_in[0];
    const int*   ei    = (const int*)d_in[1];
    const float* eattr = (const float*)d_in[2];
    const int*   batch = (const int*)d_in[3];
    const float* emb   = (const float*)d_in[4];
    const float* eW1   = (const float*)d_in[5];
    const float* eb1   = (const float*)d_in[6];
    const float* eW2   = (const float*)d_in[7];
    const float* eb2   = (const float*)d_in[8];
    const float* nW1   = (const float*)d_in[9];
    const float* nb1   = (const float*)d_in[10];
    const float* nW2   = (const float*)d_in[11];
    const float* nb2   = (const float*)d_in[12];
    const float* gam   = (const float*)d_in[13];
    const float* bet   = (const float*)d_in[14];
    const float* oW1   = (const float*)d_in[15];
    const float* ob1   = (const float*)d_in[16];
    const float* oW2   = (const float*)d_in[17];
    const float* ob2   = (const float*)d_in[18];
    const int* esrc = ei;
    const int* edst = ei + N_EDGES;

    float* x     = (float*)d_ws;
    float* y     = x + (size_t)N_NODES * DIM;
    float* aggr  = y + (size_t)N_NODES * DIM;
    float* stats = aggr + (size_t)N_NODES * HID;     // 256 floats (adjacent to aggr: joint memset)
    float* psum  = stats + 256;
    float* pcnt  = psum + NGRAPH * 64;
    __hip_bfloat16* xb = (__hip_bfloat16*)(pcnt + NGRAPH);
    short* ew1T = (short*)(xb + (size_t)N_NODES * DIM);   // [3][128][128]
    short* ew2T = ew1T + 3 * 128 * 128;                   // [3][128][128]
    short* nw1T = ew2T + 3 * 128 * 128;                   // [3][128][192]
    short* nw2T = nw1T + 3 * 128 * 192;                   // [3][64][128]

    k_embed<<<(N_NODES * DIM + 255) / 256, 256, 0, stream>>>(az, emb, x, xb);

    // pre-transpose all layer weights to bf16 [n][k]
    k_wprep<<<dim3(64, 3), 256, 0, stream>>>(eW1, ew1T, 128 * 128, 7, 129 * 128);
    k_wprep<<<dim3(64, 3), 256, 0, stream>>>(eW2, ew2T, 128 * 128, 7, 128 * 128);
    k_wprep<<<dim3(96, 3), 256, 0, stream>>>(nW1, nw1T, 192 * 128, 7, 192 * 128);
    k_wprep<<<dim3(32, 3), 256, 0, stream>>>(nW2, nw2T, 128 * 64, 6, 128 * 64);

    for (int l = 0; l < 3; l++) {
        hipMemsetAsync(aggr, 0, ((size_t)N_NODES * HID + 256) * sizeof(float), stream);
        k_edge<<<512, 256, 0, stream>>>(xb, esrc, edst, eattr,
                                        eW1 + (size_t)l * 129 * 128, eb1 + l * 128, eb2 + l * 128,
                                        ew1T + (size_t)l * 128 * 128, ew2T + (size_t)l * 128 * 128,
                                        aggr);
        k_node<<<(N_NODES + 63) / 64, 256, 0, stream>>>(xb, x, aggr,
                                                        nw1T + (size_t)l * 128 * 192, nb1 + l * 128,
                                                        nw2T + (size_t)l * 64 * 128, nb2 + l * 64,
                                                        y, stats);
        k_bnfin<<<1, 64, 0, stream>>>(gam + l * 64, bet + l * 64, stats);
        k_bnapply<<<(N_NODES * DIM / 4 + 255) / 256, 256, 0, stream>>>(y, stats, x, xb);
    }

    hipMemsetAsync(psum, 0, (NGRAPH * 64 + NGRAPH) * sizeof(float), stream);
    k_pool<<<(N_NODES + 3) / 4, 256, 0, stream>>>(batch, x, psum, pcnt);
    k_out<<<NGRAPH, 128, 0, stream>>>(psum, pcnt, oW1, ob1, oW2, ob2, (float*)d_out);
}

// Round 5
// 1475.491 us; speedup vs baseline: 2.3052x; 1.0575x over previous
//
#include <hip/hip_runtime.h>
#include <hip/hip_bf16.h>

#define N_NODES 50000
#define N_EDGES 800000
#define DIM 64
#define HID 128
#define NGRAPH 128
#define BN_EPS 1e-5f

typedef __attribute__((ext_vector_type(8))) short short8;
typedef __attribute__((ext_vector_type(4))) short short4v;
typedef __attribute__((ext_vector_type(4))) float f32x4;
typedef __attribute__((ext_vector_type(4))) int int4v;

__device__ __forceinline__ float sp_(float v) {
    // softplus via hardware v_exp_f32 / v_log_f32 (~1e-6 abs err, fine at bf16)
    return fmaxf(v, 0.f) + __logf(1.f + __expf(-fabsf(v)));
}
__device__ __forceinline__ short bfb(float f) {
    __hip_bfloat16 h = __float2bfloat16(f);
    return __builtin_bit_cast(short, h);
}
__device__ __forceinline__ float b2f(short s) {
    unsigned u = ((unsigned)(unsigned short)s) << 16;
    return __builtin_bit_cast(float, u);
}

// ---------------------------------------------------------------- embed
__global__ void k_embed(const int* __restrict__ az, const float* __restrict__ emb,
                        float* __restrict__ x, __hip_bfloat16* __restrict__ xb) {
    int idx = blockIdx.x * 256 + threadIdx.x;
    if (idx >= N_NODES * DIM) return;
    int n = idx >> 6;
    int d = idx & 63;
    float v = emb[az[n] * DIM + d];
    x[idx] = v;
    xb[idx] = __float2bfloat16(v);
}

// ---------------------------------------------------------------- weight prep:
// transpose f32 [K][N] (row-major) -> bf16 [N][K]; blockIdx.y = layer
__global__ void k_wprep(const float* __restrict__ src, short* __restrict__ dst,
                        int total, int nshift, int srcStride) {
    int l = blockIdx.y;
    int idx = blockIdx.x * 256 + threadIdx.x;
    if (idx >= total) return;
    int K = total >> nshift;
    int k = idx >> nshift;
    int n = idx & ((1 << nshift) - 1);
    dst[(size_t)l * total + n * K + k] = bfb(src[(size_t)l * srcStride + idx]);
}

// ---------------------------------------------------------------- counting sort by dst
__global__ void k_hist(const int* __restrict__ edst, int* __restrict__ deg) {
    int e = blockIdx.x * 256 + threadIdx.x;
    if (e < N_EDGES) atomicAdd(&deg[edst[e]], 1);
}

// single block, 1024 threads: exclusive prefix sum deg -> cursor
__global__ void k_scan(const int* __restrict__ deg, int* __restrict__ cursor) {
    __shared__ int wsum[16];
    __shared__ int carry;
    const int t = threadIdx.x, lane = t & 63, w = t >> 6;
    if (t == 0) carry = 0;
    __syncthreads();
    for (int base = 0; base < N_NODES; base += 1024) {
        int i = base + t;
        int v = (i < N_NODES) ? deg[i] : 0;
        int s = v;
#pragma unroll
        for (int off = 1; off < 64; off <<= 1) {
            int u = __shfl_up(s, off);
            if (lane >= off) s += u;
        }
        if (lane == 63) wsum[w] = s;
        __syncthreads();
        if (w == 0) {
            int ws = (lane < 16) ? wsum[lane] : 0;
#pragma unroll
            for (int off = 1; off < 16; off <<= 1) {
                int u = __shfl_up(ws, off);
                if (lane >= off) ws += u;
            }
            if (lane < 16) wsum[lane] = ws;
        }
        __syncthreads();
        int woff = (w == 0) ? 0 : wsum[w - 1];
        int excl = carry + woff + s - v;
        if (i < N_NODES) cursor[i] = excl;
        __syncthreads();
        if (t == 1023) carry += wsum[15];
        __syncthreads();
    }
}

__global__ void k_scatter(const int* __restrict__ esrc, const int* __restrict__ edst,
                          const float* __restrict__ eattr, int* __restrict__ cursor,
                          int* __restrict__ ssrc, int* __restrict__ sdst,
                          float* __restrict__ sattr) {
    int e = blockIdx.x * 256 + threadIdx.x;
    if (e >= N_EDGES) return;
    int d = edst[e];
    int pos = atomicAdd(&cursor[d], 1);
    ssrc[pos] = esrc[e];
    sdst[pos] = d;
    sattr[pos] = eattr[e];
}

// ---------------------------------------------------------------- edge MLP (dst-sorted edges)
// tile = 64 edges, 4 waves, N=128 cols (32/wave), K=128 (+rank-1 attr term)
// weights in registers; epilogue: m-tile -> LDS (bf16), per-segment reduce,
// ONE atomicAdd per (segment,col) instead of per (edge,col).
__launch_bounds__(256, 4)
__global__ void k_edge(const __hip_bfloat16* __restrict__ xb,
                       const int* __restrict__ ssrc, const int* __restrict__ sdst,
                       const float* __restrict__ sattr,
                       const float* __restrict__ W1f, const float* __restrict__ b1,
                       const float* __restrict__ b2,
                       const short* __restrict__ w1T, const short* __restrict__ w2T,
                       float* __restrict__ aggr) {
    __shared__ short zt[64 * 128];     // 16KB; phase2: reused as bf16 m-tile
    __shared__ short ht[64 * 128];     // 16KB
    __shared__ float attr_s[64];
    __shared__ int   dst_s[64];
    __shared__ int   seg_start[65];
    __shared__ int   seg_dst[64];
    __shared__ int   nseg_s;

    const int t = threadIdx.x;
    const int wid = t >> 6, lane = t & 63;
    const int lrow = lane & 15, lk = lane >> 4;
    const int r = t >> 2, q = t & 3;
    const int nc0 = wid * 32;

    // preload weight fragments + per-col scalars into registers
    short8 w1f[4][2], w2f[4][2];
    float b1v[2], b2v[2], wlv[2];
#pragma unroll
    for (int ni = 0; ni < 2; ni++) {
        int col = nc0 + ni * 16 + lrow;
#pragma unroll
        for (int ks = 0; ks < 4; ks++) {
            int kb = ks * 64 + lk * 16;
            w1f[ks][ni] = *(const short8*)((const char*)w1T + col * 256 + kb);
            w2f[ks][ni] = *(const short8*)((const char*)w2T + col * 256 + kb);
        }
        b1v[ni] = b1[col];
        b2v[ni] = b2[col];
        wlv[ni] = W1f[128 * 128 + col];   // attr rank-1 row (f32 original)
    }

    for (int tile = blockIdx.x; tile < N_EDGES / 64; tile += gridDim.x) {
        const int e0 = tile * 64;
        // ---- stage z tile: cols 0..63 = x[dst], 64..127 = x[src]
        {
            int e = e0 + r;
            int dn = sdst[e], sn = ssrc[e];
            if (q == 0) { dst_s[r] = dn; attr_s[r] = sattr[e]; }
            const __hip_bfloat16* xr = xb + (size_t)(q < 2 ? dn : sn) * DIM + (q & 1) * 32;
#pragma unroll
            for (int i = 0; i < 4; i++) {
                int4v v = *(const int4v*)(xr + i * 8);
                int cb = q * 64 + i * 16;
                *(int4v*)((char*)zt + r * 256 + (cb ^ ((r & 7) << 4))) = v;
            }
        }
        __syncthreads();                       // A: z tile + dst_s ready

        // ---- segment list (wave 0): boundaries where sorted dst changes
        if (wid == 0) {
            int d = dst_s[lane];
            int prev = (lane == 0) ? -1 : dst_s[lane - 1];
            bool start = (d != prev);
            unsigned long long mask = __ballot(start);
            int sidx = __popcll(mask & ((1ull << lane) - 1));
            if (start) { seg_start[sidx] = lane; seg_dst[sidx] = d; }
            if (lane == 63) {
                int ns = __popcll(mask);
                nseg_s = ns;
                seg_start[ns] = 64;
            }
        }

        // ---- GEMM1: [64x128] @ [128x128]
        f32x4 acc[4][2];
#pragma unroll
        for (int mi = 0; mi < 4; mi++)
#pragma unroll
            for (int ni = 0; ni < 2; ni++) acc[mi][ni] = (f32x4){0.f, 0.f, 0.f, 0.f};
#pragma unroll
        for (int ks = 0; ks < 4; ks++) {
            int kb = ks * 64 + lk * 16;
            short8 av[4];
#pragma unroll
            for (int mi = 0; mi < 4; mi++) {
                int row = mi * 16 + lrow;
                av[mi] = *(const short8*)((const char*)zt + row * 256 + (kb ^ ((row & 7) << 4)));
            }
#pragma unroll
            for (int mi = 0; mi < 4; mi++)
#pragma unroll
                for (int ni = 0; ni < 2; ni++)
                    acc[mi][ni] = __builtin_amdgcn_mfma_f32_16x16x32_bf16(av[mi], w1f[ks][ni], acc[mi][ni], 0, 0, 0);
        }
        // epilogue 1: + b1 + attr * W1_lastrow, softplus, -> ht (bf16)
#pragma unroll
        for (int mi = 0; mi < 4; mi++) {
#pragma unroll
            for (int ni = 0; ni < 2; ni++) {
                int col = nc0 + ni * 16 + lrow;
#pragma unroll
                for (int rr = 0; rr < 4; rr++) {
                    int row = mi * 16 + lk * 4 + rr;
                    float val = acc[mi][ni][rr] + b1v[ni] + attr_s[row] * wlv[ni];
                    *(short*)((char*)ht + row * 256 + ((col * 2) ^ ((row & 7) << 4))) = bfb(sp_(val));
                }
            }
        }
        __syncthreads();                       // B: all zt reads done, ht ready

        // ---- GEMM2: [64x128] @ [128x128]
        f32x4 acc2[4][2];
#pragma unroll
        for (int mi = 0; mi < 4; mi++)
#pragma unroll
            for (int ni = 0; ni < 2; ni++) acc2[mi][ni] = (f32x4){0.f, 0.f, 0.f, 0.f};
#pragma unroll
        for (int ks = 0; ks < 4; ks++) {
            int kb = ks * 64 + lk * 16;
            short8 av[4];
#pragma unroll
            for (int mi = 0; mi < 4; mi++) {
                int row = mi * 16 + lrow;
                av[mi] = *(const short8*)((const char*)ht + row * 256 + (kb ^ ((row & 7) << 4)));
            }
#pragma unroll
            for (int mi = 0; mi < 4; mi++)
#pragma unroll
                for (int ni = 0; ni < 2; ni++)
                    acc2[mi][ni] = __builtin_amdgcn_mfma_f32_16x16x32_bf16(av[mi], w2f[ks][ni], acc2[mi][ni], 0, 0, 0);
        }
        // epilogue 2: softplus(+b2) -> m-tile in LDS (bf16, reuses zt)
#pragma unroll
        for (int mi = 0; mi < 4; mi++) {
#pragma unroll
            for (int ni = 0; ni < 2; ni++) {
                int col = nc0 + ni * 16 + lrow;
#pragma unroll
                for (int rr = 0; rr < 4; rr++) {
                    int row = mi * 16 + lk * 4 + rr;
                    float val = sp_(acc2[mi][ni][rr] + b2v[ni]);
                    *(short*)((char*)zt + row * 256 + ((col * 2) ^ ((row & 7) << 4))) = bfb(val);
                }
            }
        }
        __syncthreads();                       // C: m-tile visible to all

        // ---- per-segment reduce + one atomicAdd per (segment, col)
        {
            int nseg = nseg_s;
            int col = t & 127, h = t >> 7;
            for (int s = h; s < nseg; s += 2) {
                int r0 = seg_start[s], r1 = seg_start[s + 1];
                float sum = 0.f;
                for (int rr = r0; rr < r1; rr++)
                    sum += b2f(*(const short*)((const char*)zt + rr * 256 + ((col * 2) ^ ((rr & 7) << 4))));
                atomicAdd(&aggr[(size_t)seg_dst[s] * HID + col], sum);
            }
        }
        __syncthreads();                       // D: reduce done, zt/seg reusable
    }
}

// ---------------------------------------------------------------- node MLP + BN partial stats
// tile = 64 nodes, K=192 (x||aggr) -> H=128 -> sp -> K=128 -> D=64, +x residual
__launch_bounds__(256, 3)
__global__ void k_node(const __hip_bfloat16* __restrict__ xb,
                       const float* __restrict__ xf,
                       const float* __restrict__ aggr,
                       const short* __restrict__ w1T, const float* __restrict__ b1,
                       const short* __restrict__ w2T, const float* __restrict__ b2,
                       float* __restrict__ y, float* __restrict__ stats) {
    __shared__ short at[64 * 192];    // 24KB rowbytes 384
    __shared__ short ht[64 * 128];    // 16KB

    const int t = threadIdx.x;
    const int wid = t >> 6, lane = t & 63, lrow = lane & 15, lk = lane >> 4;
    const int n0 = blockIdx.x * 64;

    // preload weight fragments
    const int nc0 = wid * 32;
    short8 w1f[6][2];
    float b1v[2];
#pragma unroll
    for (int ni = 0; ni < 2; ni++) {
        int col = nc0 + ni * 16 + lrow;
#pragma unroll
        for (int ks = 0; ks < 6; ks++) {
            int kb = ks * 64 + lk * 16;
            w1f[ks][ni] = *(const short8*)((const char*)w1T + col * 384 + kb);
        }
        b1v[ni] = b1[col];
    }
    const int nc2 = wid * 16;
    const int col2 = nc2 + lrow;
    short8 w2f[4];
#pragma unroll
    for (int ks = 0; ks < 4; ks++)
        w2f[ks] = *(const short8*)((const char*)w2T + col2 * 256 + ks * 64 + lk * 16);
    const float b2v = b2[col2];

    // stage A rows: [x bf16 (64) || aggr f32->bf16 (128)]
    if (t < 64) {
        int node = n0 + t;
        if (node < N_NODES) {
            const __hip_bfloat16* xr = xb + (size_t)node * DIM;
#pragma unroll
            for (int i = 0; i < 8; i++) {
                int4v v = *(const int4v*)(xr + i * 8);
                *(int4v*)((char*)at + t * 384 + ((i * 16) ^ ((t & 7) << 4))) = v;
            }
        } else {
            int4v z = {0, 0, 0, 0};
#pragma unroll
            for (int i = 0; i < 8; i++)
                *(int4v*)((char*)at + t * 384 + ((i * 16) ^ ((t & 7) << 4))) = z;
        }
    }
    {
        int r = t >> 2, q = t & 3;
        int node = n0 + r;
#pragma unroll
        for (int i = 0; i < 4; i++) {
            short8 s = {0, 0, 0, 0, 0, 0, 0, 0};
            if (node < N_NODES) {
                const float* ar = aggr + (size_t)node * HID + q * 32 + i * 8;
                float4 f0 = *(const float4*)ar;
                float4 f1 = *(const float4*)(ar + 4);
                s = (short8){bfb(f0.x), bfb(f0.y), bfb(f0.z), bfb(f0.w),
                             bfb(f1.x), bfb(f1.y), bfb(f1.z), bfb(f1.w)};
            }
            int cb = 128 + q * 64 + i * 16;
            *(short8*)((char*)at + r * 384 + (cb ^ ((r & 7) << 4))) = s;
        }
    }
    __syncthreads();

    // GEMM1: [64x192] @ [192x128]
    f32x4 acc[4][2];
#pragma unroll
    for (int mi = 0; mi < 4; mi++)
#pragma unroll
        for (int ni = 0; ni < 2; ni++) acc[mi][ni] = (f32x4){0.f, 0.f, 0.f, 0.f};
#pragma unroll
    for (int ks = 0; ks < 6; ks++) {
        int kb = ks * 64 + lk * 16;
        short8 av[4];
#pragma unroll
        for (int mi = 0; mi < 4; mi++) {
            int row = mi * 16 + lrow;
            av[mi] = *(const short8*)((const char*)at + row * 384 + (kb ^ ((row & 7) << 4)));
        }
#pragma unroll
        for (int mi = 0; mi < 4; mi++)
#pragma unroll
            for (int ni = 0; ni < 2; ni++)
                acc[mi][ni] = __builtin_amdgcn_mfma_f32_16x16x32_bf16(av[mi], w1f[ks][ni], acc[mi][ni], 0, 0, 0);
    }
#pragma unroll
    for (int mi = 0; mi < 4; mi++) {
#pragma unroll
        for (int ni = 0; ni < 2; ni++) {
            int col = nc0 + ni * 16 + lrow;
#pragma unroll
            for (int rr = 0; rr < 4; rr++) {
                int row = mi * 16 + lk * 4 + rr;
                float val = sp_(acc[mi][ni][rr] + b1v[ni]);
                *(short*)((char*)ht + row * 256 + ((col * 2) ^ ((row & 7) << 4))) = bfb(val);
            }
        }
    }
    __syncthreads();

    // GEMM2: [64x128] @ [128x64], each wave owns 16 output cols
    f32x4 acc2[4];
#pragma unroll
    for (int mi = 0; mi < 4; mi++) acc2[mi] = (f32x4){0.f, 0.f, 0.f, 0.f};
#pragma unroll
    for (int ks = 0; ks < 4; ks++) {
        int kb = ks * 64 + lk * 16;
        short8 av[4];
#pragma unroll
        for (int mi = 0; mi < 4; mi++) {
            int row = mi * 16 + lrow;
            av[mi] = *(const short8*)((const char*)ht + row * 256 + (kb ^ ((row & 7) << 4)));
        }
#pragma unroll
        for (int mi = 0; mi < 4; mi++)
            acc2[mi] = __builtin_amdgcn_mfma_f32_16x16x32_bf16(av[mi], w2f[ks], acc2[mi], 0, 0, 0);
    }
    // epilogue: +b2 +x residual, write y, BN partial sums
    float s1 = 0.f, s2 = 0.f;
#pragma unroll
    for (int mi = 0; mi < 4; mi++) {
#pragma unroll
        for (int rr = 0; rr < 4; rr++) {
            int row = mi * 16 + lk * 4 + rr;
            int node = n0 + row;
            if (node < N_NODES) {
                float v = acc2[mi][rr] + b2v + xf[(size_t)node * DIM + col2];
                y[(size_t)node * DIM + col2] = v;
                s1 += v;
                s2 += v * v;
            }
        }
    }
    s1 += __shfl_xor(s1, 16); s1 += __shfl_xor(s1, 32);
    s2 += __shfl_xor(s2, 16); s2 += __shfl_xor(s2, 32);
    if (lane < 16) {
        atomicAdd(&stats[col2], s1);
        atomicAdd(&stats[64 + col2], s2);
    }
}

// ---------------------------------------------------------------- BN finalize: a=gamma*rstd, b=beta-mu*a
__global__ void k_bnfin(const float* __restrict__ gamma, const float* __restrict__ beta,
                        float* __restrict__ stats) {
    int d = threadIdx.x;
    float mu = stats[d] * (1.f / N_NODES);
    float var = stats[64 + d] * (1.f / N_NODES) - mu * mu;
    float rstd = rsqrtf(var + BN_EPS);
    float a = gamma[d] * rstd;
    stats[128 + d] = a;
    stats[192 + d] = beta[d] - mu * a;
}

// ---------------------------------------------------------------- BN apply -> new x (f32 + bf16)
__global__ void k_bnapply(const float* __restrict__ y, const float* __restrict__ stats,
                          float* __restrict__ x, __hip_bfloat16* __restrict__ xb) {
    int idx = (blockIdx.x * 256 + threadIdx.x) * 4;
    if (idx >= N_NODES * DIM) return;
    int d = idx & 63;
    float4 v = *(const float4*)(y + idx);
    float4 r;
    r.x = stats[128 + d + 0] * v.x + stats[192 + d + 0];
    r.y = stats[128 + d + 1] * v.y + stats[192 + d + 1];
    r.z = stats[128 + d + 2] * v.z + stats[192 + d + 2];
    r.w = stats[128 + d + 3] * v.w + stats[192 + d + 3];
    *(float4*)(x + idx) = r;
    short4v s = {bfb(r.x), bfb(r.y), bfb(r.z), bfb(r.w)};
    *(short4v*)((char*)(xb + idx)) = s;
}

// ---------------------------------------------------------------- pool (atomic mean prep)
__global__ void k_pool(const int* __restrict__ batch, const float* __restrict__ x,
                       float* __restrict__ psum, float* __restrict__ pcnt) {
    int t = threadIdx.x;
    int nloc = t >> 6, d = t & 63;
    int node = blockIdx.x * 4 + nloc;
    if (node >= N_NODES) return;
    int g = batch[node];
    atomicAdd(&psum[g * 64 + d], x[(size_t)node * 64 + d]);
    if (d == 0) atomicAdd(&pcnt[g], 1.f);
}

// ---------------------------------------------------------------- output MLP (f32)
__global__ void k_out(const float* __restrict__ psum, const float* __restrict__ pcnt,
                      const float* __restrict__ W1, const float* __restrict__ b1,
                      const float* __restrict__ W2, const float* __restrict__ b2,
                      float* __restrict__ out) {
    __shared__ float pl[64];
    __shared__ float wsum[2];
    int g = blockIdx.x, t = threadIdx.x;
    if (t < 64) pl[t] = psum[g * 64 + t] / fmaxf(pcnt[g], 1.f);
    __syncthreads();
    float a = b1[t];
#pragma unroll
    for (int d = 0; d < 64; d++) a += pl[d] * W1[d * 128 + t];
    float c = sp_(a) * W2[t];
#pragma unroll
    for (int off = 32; off >= 1; off >>= 1) c += __shfl_down(c, off);
    int lane = t & 63, wid = t >> 6;
    if (lane == 0) wsum[wid] = c;
    __syncthreads();
    if (t == 0) out[g] = wsum[0] + wsum[1] + b2[0];
}

// ---------------------------------------------------------------- launch
extern "C" void kernel_launch(void* const* d_in, const int* in_sizes, int n_in,
                              void* d_out, int out_size, void* d_ws, size_t ws_size,
                              hipStream_t stream) {
    const int*   az    = (const int*)d_in[0];
    const int*   ei    = (const int*)d_in[1];
    const float* eattr = (const float*)d_in[2];
    const int*   batch = (const int*)d_in[3];
    const float* emb   = (const float*)d_in[4];
    const float* eW1   = (const float*)d_in[5];
    const float* eb1   = (const float*)d_in[6];
    const float* eW2   = (const float*)d_in[7];
    const float* eb2   = (const float*)d_in[8];
    const float* nW1   = (const float*)d_in[9];
    const float* nb1   = (const float*)d_in[10];
    const float* nW2   = (const float*)d_in[11];
    const float* nb2   = (const float*)d_in[12];
    const float* gam   = (const float*)d_in[13];
    const float* bet   = (const float*)d_in[14];
    const float* oW1   = (const float*)d_in[15];
    const float* ob1   = (const float*)d_in[16];
    const float* oW2   = (const float*)d_in[17];
    const float* ob2   = (const float*)d_in[18];
    const int* esrc = ei;
    const int* edst = ei + N_EDGES;

    float* x     = (float*)d_ws;
    float* y     = x + (size_t)N_NODES * DIM;
    float* aggr  = y + (size_t)N_NODES * DIM;
    float* stats = aggr + (size_t)N_NODES * HID;     // 256 floats (adjacent: joint memset)
    float* psum  = stats + 256;
    float* pcnt  = psum + NGRAPH * 64;
    __hip_bfloat16* xb = (__hip_bfloat16*)(pcnt + NGRAPH);
    short* ew1T = (short*)(xb + (size_t)N_NODES * DIM);   // [3][128][128]
    short* ew2T = ew1T + 3 * 128 * 128;                   // [3][128][128]
    short* nw1T = ew2T + 3 * 128 * 128;                   // [3][128][192]
    short* nw2T = nw1T + 3 * 128 * 192;                   // [3][64][128]
    int*   cursor = (int*)(nw2T + 3 * 64 * 128);          // [50000]
    int*   ssrc   = cursor + N_NODES;                     // [800000]
    int*   sdstA  = ssrc + N_EDGES;                       // [800000]
    float* sattr  = (float*)(sdstA + N_EDGES);            // [800000]

    k_embed<<<(N_NODES * DIM + 255) / 256, 256, 0, stream>>>(az, emb, x, xb);

    // pre-transpose all layer weights to bf16 [n][k]
    k_wprep<<<dim3(64, 3), 256, 0, stream>>>(eW1, ew1T, 128 * 128, 7, 129 * 128);
    k_wprep<<<dim3(64, 3), 256, 0, stream>>>(eW2, ew2T, 128 * 128, 7, 128 * 128);
    k_wprep<<<dim3(96, 3), 256, 0, stream>>>(nW1, nw1T, 192 * 128, 7, 192 * 128);
    k_wprep<<<dim3(32, 3), 256, 0, stream>>>(nW2, nw2T, 128 * 64, 6, 128 * 64);

    // counting sort of edges by dst (once per launch; reused by all 3 layers)
    hipMemsetAsync(cursor, 0, N_NODES * sizeof(int), stream);
    k_hist<<<(N_EDGES + 255) / 256, 256, 0, stream>>>(edst, cursor);
    k_scan<<<1, 1024, 0, stream>>>(cursor, cursor);   // in-place: per-thread own-index RMW
    k_scatter<<<(N_EDGES + 255) / 256, 256, 0, stream>>>(esrc, edst, eattr, cursor,
                                                         ssrc, sdstA, sattr);

    for (int l = 0; l < 3; l++) {
        hipMemsetAsync(aggr, 0, ((size_t)N_NODES * HID + 256) * sizeof(float), stream);
        k_edge<<<1024, 256, 0, stream>>>(xb, ssrc, sdstA, sattr,
                                         eW1 + (size_t)l * 129 * 128, eb1 + l * 128, eb2 + l * 128,
                                         ew1T + (size_t)l * 128 * 128, ew2T + (size_t)l * 128 * 128,
                                         aggr);
        k_node<<<(N_NODES + 63) / 64, 256, 0, stream>>>(xb, x, aggr,
                                                        nw1T + (size_t)l * 128 * 192, nb1 + l * 128,
                                                        nw2T + (size_t)l * 64 * 128, nb2 + l * 64,
                                                        y, stats);
        k_bnfin<<<1, 64, 0, stream>>>(gam + l * 64, bet + l * 64, stats);
        k_bnapply<<<(N_NODES * DIM / 4 + 255) / 256, 256, 0, stream>>>(y, stats, x, xb);
    }

    hipMemsetAsync(psum, 0, (NGRAPH * 64 + NGRAPH) * sizeof(float), stream);
    k_pool<<<(N_NODES + 3) / 4, 256, 0, stream>>>(batch, x, psum, pcnt);
    k_out<<<NGRAPH, 128, 0, stream>>>(psum, pcnt, oW1, ob1, oW2, ob2, (float*)d_out);
}

// Round 6
// 1298.853 us; speedup vs baseline: 2.6187x; 1.1360x over previous
//
#include <hip/hip_runtime.h>
#include <hip/hip_bf16.h>

#define N_NODES 50000
#define N_EDGES 800000
#define DIM 64
#define HID 128
#define NGRAPH 128
#define BN_EPS 1e-5f

typedef __attribute__((ext_vector_type(8))) short short8;
typedef __attribute__((ext_vector_type(4))) short short4v;
typedef __attribute__((ext_vector_type(4))) float f32x4;
typedef __attribute__((ext_vector_type(4))) int int4v;

__device__ __forceinline__ float sp_(float v) {
    // softplus via hardware v_exp_f32 / v_log_f32 (~1e-6 abs err, fine at bf16)
    return fmaxf(v, 0.f) + __logf(1.f + __expf(-fabsf(v)));
}
__device__ __forceinline__ short bfb(float f) {
    __hip_bfloat16 h = __float2bfloat16(f);
    return __builtin_bit_cast(short, h);
}
__device__ __forceinline__ float b2f(short s) {
    unsigned u = ((unsigned)(unsigned short)s) << 16;
    return __builtin_bit_cast(float, u);
}

// ---------------------------------------------------------------- embed
__global__ void k_embed(const int* __restrict__ az, const float* __restrict__ emb,
                        float* __restrict__ x, __hip_bfloat16* __restrict__ xb) {
    int idx = blockIdx.x * 256 + threadIdx.x;
    if (idx >= N_NODES * DIM) return;
    int n = idx >> 6;
    int d = idx & 63;
    float v = emb[az[n] * DIM + d];
    x[idx] = v;
    xb[idx] = __float2bfloat16(v);
}

// ---------------------------------------------------------------- weight prep:
// transpose f32 [K][N] (row-major) -> bf16 [N][K]; blockIdx.y = layer
__global__ void k_wprep(const float* __restrict__ src, short* __restrict__ dst,
                        int total, int nshift, int srcStride) {
    int l = blockIdx.y;
    int idx = blockIdx.x * 256 + threadIdx.x;
    if (idx >= total) return;
    int K = total >> nshift;
    int k = idx >> nshift;
    int n = idx & ((1 << nshift) - 1);
    dst[(size_t)l * total + n * K + k] = bfb(src[(size_t)l * srcStride + idx]);
}

// ---------------------------------------------------------------- counting sort by dst
__global__ void k_hist(const int* __restrict__ edst, int* __restrict__ deg) {
    int e = blockIdx.x * 256 + threadIdx.x;
    if (e < N_EDGES) atomicAdd(&deg[edst[e]], 1);
}

// single block, 1024 threads: exclusive prefix sum deg -> cursor
__global__ void k_scan(const int* __restrict__ deg, int* __restrict__ cursor) {
    __shared__ int wsum[16];
    __shared__ int carry;
    const int t = threadIdx.x, lane = t & 63, w = t >> 6;
    if (t == 0) carry = 0;
    __syncthreads();
    for (int base = 0; base < N_NODES; base += 1024) {
        int i = base + t;
        int v = (i < N_NODES) ? deg[i] : 0;
        int s = v;
#pragma unroll
        for (int off = 1; off < 64; off <<= 1) {
            int u = __shfl_up(s, off);
            if (lane >= off) s += u;
        }
        if (lane == 63) wsum[w] = s;
        __syncthreads();
        if (w == 0) {
            int ws = (lane < 16) ? wsum[lane] : 0;
#pragma unroll
            for (int off = 1; off < 16; off <<= 1) {
                int u = __shfl_up(ws, off);
                if (lane >= off) ws += u;
            }
            if (lane < 16) wsum[lane] = ws;
        }
        __syncthreads();
        int woff = (w == 0) ? 0 : wsum[w - 1];
        int excl = carry + woff + s - v;
        if (i < N_NODES) cursor[i] = excl;
        __syncthreads();
        if (t == 1023) carry += wsum[15];
        __syncthreads();
    }
}

__global__ void k_scatter(const int* __restrict__ esrc, const int* __restrict__ edst,
                          const float* __restrict__ eattr, int* __restrict__ cursor,
                          int* __restrict__ ssrc, int* __restrict__ sdst,
                          float* __restrict__ sattr) {
    int e = blockIdx.x * 256 + threadIdx.x;
    if (e >= N_EDGES) return;
    int d = edst[e];
    int pos = atomicAdd(&cursor[d], 1);
    ssrc[pos] = esrc[e];
    sdst[pos] = d;
    sattr[pos] = eattr[e];
}

// ---------------------------------------------------------------- edge MLP (dst-sorted edges)
// 512 threads / 8 waves, 16 output cols per wave -> weight frags fit in regs
// (32 VGPR weights + 32 AGPR acc, no spill at 4 waves/SIMD). Contiguous
// 25-tile chunk per block for dst-gather L1 locality. Epilogue: bf16 m-tile
// in LDS, per-segment reduce, one atomicAdd per (segment, col).
__launch_bounds__(512, 4)
__global__ void k_edge(const __hip_bfloat16* __restrict__ xb,
                       const int* __restrict__ ssrc, const int* __restrict__ sdst,
                       const float* __restrict__ sattr,
                       const float* __restrict__ W1f, const float* __restrict__ b1,
                       const float* __restrict__ b2,
                       const short* __restrict__ w1T, const short* __restrict__ w2T,
                       float* __restrict__ aggr) {
    __shared__ short zt[64 * 128];     // 16KB; phase2: reused as bf16 m-tile
    __shared__ short ht[64 * 128];     // 16KB
    __shared__ float attr_s[64];
    __shared__ int   dst_s[64];
    __shared__ int   seg_start[65];
    __shared__ int   seg_dst[64];
    __shared__ int   nseg_s;

    const int t = threadIdx.x;
    const int wid = t >> 6, lane = t & 63;
    const int lrow = lane & 15, lk = lane >> 4;
    const int r = t >> 3, q = t & 7;          // staging: 8 threads per edge row
    const int col = wid * 16 + lrow;          // this thread's output column

    // preload weight fragments + per-col scalars into registers (16 cols/wave)
    short8 w1f[4], w2f[4];
#pragma unroll
    for (int ks = 0; ks < 4; ks++) {
        int kb = ks * 64 + lk * 16;
        w1f[ks] = *(const short8*)((const char*)w1T + col * 256 + kb);
        w2f[ks] = *(const short8*)((const char*)w2T + col * 256 + kb);
    }
    const float b1v = b1[col];
    const float b2v = b2[col];
    const float wlv = W1f[128 * 128 + col];   // attr rank-1 row (f32 original)

    const int NT = N_EDGES / 64;              // 12500
    const int tile0 = blockIdx.x * 25;
    const int tile1 = (tile0 + 25 < NT) ? tile0 + 25 : NT;

    for (int tile = tile0; tile < tile1; ++tile) {
        const int e0 = tile * 64;
        // ---- stage z tile: cols 0..63 = x[dst], 64..127 = x[src]; 32B/thread
        {
            int e = e0 + r;
            int dn = sdst[e], sn = ssrc[e];
            if (q == 0) { dst_s[r] = dn; attr_s[r] = sattr[e]; }
            int node = (q < 4) ? dn : sn;
            const __hip_bfloat16* xr = xb + (size_t)node * DIM + (q & 3) * 16;
            int4v v0 = *(const int4v*)(xr);
            int4v v1 = *(const int4v*)(xr + 8);
            int cb = (q >> 2) * 128 + (q & 3) * 32;
            *(int4v*)((char*)zt + r * 256 + (cb ^ ((r & 7) << 4))) = v0;
            *(int4v*)((char*)zt + r * 256 + ((cb + 16) ^ ((r & 7) << 4))) = v1;
        }
        __syncthreads();                       // A: z tile + dst_s ready

        // ---- segment list (wave 0): boundaries where sorted dst changes
        if (wid == 0) {
            int d = dst_s[lane];
            int prev = (lane == 0) ? -1 : dst_s[lane - 1];
            bool start = (d != prev);
            unsigned long long mask = __ballot(start);
            int sidx = __popcll(mask & ((1ull << lane) - 1));
            if (start) { seg_start[sidx] = lane; seg_dst[sidx] = d; }
            if (lane == 63) {
                int ns = __popcll(mask);
                nseg_s = ns;
                seg_start[ns] = 64;
            }
        }

        // ---- GEMM1: [64x128] @ [128x128], wave owns 16 cols
        f32x4 acc[4];
#pragma unroll
        for (int mi = 0; mi < 4; mi++) acc[mi] = (f32x4){0.f, 0.f, 0.f, 0.f};
#pragma unroll
        for (int ks = 0; ks < 4; ks++) {
            int kb = ks * 64 + lk * 16;
            short8 av[4];
#pragma unroll
            for (int mi = 0; mi < 4; mi++) {
                int row = mi * 16 + lrow;
                av[mi] = *(const short8*)((const char*)zt + row * 256 + (kb ^ ((row & 7) << 4)));
            }
#pragma unroll
            for (int mi = 0; mi < 4; mi++)
                acc[mi] = __builtin_amdgcn_mfma_f32_16x16x32_bf16(av[mi], w1f[ks], acc[mi], 0, 0, 0);
        }
        // epilogue 1: + b1 + attr * W1_lastrow, softplus, -> ht (bf16)
#pragma unroll
        for (int mi = 0; mi < 4; mi++) {
#pragma unroll
            for (int rr = 0; rr < 4; rr++) {
                int row = mi * 16 + lk * 4 + rr;
                float val = acc[mi][rr] + b1v + attr_s[row] * wlv;
                *(short*)((char*)ht + row * 256 + ((col * 2) ^ ((row & 7) << 4))) = bfb(sp_(val));
            }
        }
        __syncthreads();                       // B: all zt reads done, ht ready

        // ---- GEMM2: [64x128] @ [128x128]
        f32x4 acc2[4];
#pragma unroll
        for (int mi = 0; mi < 4; mi++) acc2[mi] = (f32x4){0.f, 0.f, 0.f, 0.f};
#pragma unroll
        for (int ks = 0; ks < 4; ks++) {
            int kb = ks * 64 + lk * 16;
            short8 av[4];
#pragma unroll
            for (int mi = 0; mi < 4; mi++) {
                int row = mi * 16 + lrow;
                av[mi] = *(const short8*)((const char*)ht + row * 256 + (kb ^ ((row & 7) << 4)));
            }
#pragma unroll
            for (int mi = 0; mi < 4; mi++)
                acc2[mi] = __builtin_amdgcn_mfma_f32_16x16x32_bf16(av[mi], w2f[ks], acc2[mi], 0, 0, 0);
        }
        // epilogue 2: softplus(+b2) -> m-tile in LDS (bf16, reuses zt)
#pragma unroll
        for (int mi = 0; mi < 4; mi++) {
#pragma unroll
            for (int rr = 0; rr < 4; rr++) {
                int row = mi * 16 + lk * 4 + rr;
                float val = sp_(acc2[mi][rr] + b2v);
                *(short*)((char*)zt + row * 256 + ((col * 2) ^ ((row & 7) << 4))) = bfb(val);
            }
        }
        __syncthreads();                       // C: m-tile visible to all

        // ---- per-segment reduce + one atomicAdd per (segment, col)
        {
            int nseg = nseg_s;
            int rcol = t & 127, h = t >> 7;    // 4 thread-groups over segments
            for (int s = h; s < nseg; s += 4) {
                int r0 = seg_start[s], r1 = seg_start[s + 1];
                float sum = 0.f;
                for (int rr = r0; rr < r1; rr++)
                    sum += b2f(*(const short*)((const char*)zt + rr * 256 + ((rcol * 2) ^ ((rr & 7) << 4))));
                atomicAdd(&aggr[(size_t)seg_dst[s] * HID + rcol], sum);
            }
        }
        __syncthreads();                       // D: reduce done, zt/seg reusable
    }
}

// ---------------------------------------------------------------- node MLP + BN partial stats
// tile = 64 nodes, K=192 (x||aggr) -> H=128 -> sp -> K=128 -> D=64, +x residual
__launch_bounds__(256, 3)
__global__ void k_node(const __hip_bfloat16* __restrict__ xb,
                       const float* __restrict__ xf,
                       const float* __restrict__ aggr,
                       const short* __restrict__ w1T, const float* __restrict__ b1,
                       const short* __restrict__ w2T, const float* __restrict__ b2,
                       float* __restrict__ y, float* __restrict__ stats) {
    __shared__ short at[64 * 192];    // 24KB rowbytes 384
    __shared__ short ht[64 * 128];    // 16KB

    const int t = threadIdx.x;
    const int wid = t >> 6, lane = t & 63, lrow = lane & 15, lk = lane >> 4;
    const int n0 = blockIdx.x * 64;

    // preload weight fragments
    const int nc0 = wid * 32;
    short8 w1f[6][2];
    float b1v[2];
#pragma unroll
    for (int ni = 0; ni < 2; ni++) {
        int col = nc0 + ni * 16 + lrow;
#pragma unroll
        for (int ks = 0; ks < 6; ks++) {
            int kb = ks * 64 + lk * 16;
            w1f[ks][ni] = *(const short8*)((const char*)w1T + col * 384 + kb);
        }
        b1v[ni] = b1[col];
    }
    const int nc2 = wid * 16;
    const int col2 = nc2 + lrow;
    short8 w2f[4];
#pragma unroll
    for (int ks = 0; ks < 4; ks++)
        w2f[ks] = *(const short8*)((const char*)w2T + col2 * 256 + ks * 64 + lk * 16);
    const float b2v = b2[col2];

    // stage A rows: [x bf16 (64) || aggr f32->bf16 (128)]
    if (t < 64) {
        int node = n0 + t;
        if (node < N_NODES) {
            const __hip_bfloat16* xr = xb + (size_t)node * DIM;
#pragma unroll
            for (int i = 0; i < 8; i++) {
                int4v v = *(const int4v*)(xr + i * 8);
                *(int4v*)((char*)at + t * 384 + ((i * 16) ^ ((t & 7) << 4))) = v;
            }
        } else {
            int4v z = {0, 0, 0, 0};
#pragma unroll
            for (int i = 0; i < 8; i++)
                *(int4v*)((char*)at + t * 384 + ((i * 16) ^ ((t & 7) << 4))) = z;
        }
    }
    {
        int r = t >> 2, q = t & 3;
        int node = n0 + r;
#pragma unroll
        for (int i = 0; i < 4; i++) {
            short8 s = {0, 0, 0, 0, 0, 0, 0, 0};
            if (node < N_NODES) {
                const float* ar = aggr + (size_t)node * HID + q * 32 + i * 8;
                float4 f0 = *(const float4*)ar;
                float4 f1 = *(const float4*)(ar + 4);
                s = (short8){bfb(f0.x), bfb(f0.y), bfb(f0.z), bfb(f0.w),
                             bfb(f1.x), bfb(f1.y), bfb(f1.z), bfb(f1.w)};
            }
            int cb = 128 + q * 64 + i * 16;
            *(short8*)((char*)at + r * 384 + (cb ^ ((r & 7) << 4))) = s;
        }
    }
    __syncthreads();

    // GEMM1: [64x192] @ [192x128]
    f32x4 acc[4][2];
#pragma unroll
    for (int mi = 0; mi < 4; mi++)
#pragma unroll
        for (int ni = 0; ni < 2; ni++) acc[mi][ni] = (f32x4){0.f, 0.f, 0.f, 0.f};
#pragma unroll
    for (int ks = 0; ks < 6; ks++) {
        int kb = ks * 64 + lk * 16;
        short8 av[4];
#pragma unroll
        for (int mi = 0; mi < 4; mi++) {
            int row = mi * 16 + lrow;
            av[mi] = *(const short8*)((const char*)at + row * 384 + (kb ^ ((row & 7) << 4)));
        }
#pragma unroll
        for (int mi = 0; mi < 4; mi++)
#pragma unroll
            for (int ni = 0; ni < 2; ni++)
                acc[mi][ni] = __builtin_amdgcn_mfma_f32_16x16x32_bf16(av[mi], w1f[ks][ni], acc[mi][ni], 0, 0, 0);
    }
#pragma unroll
    for (int mi = 0; mi < 4; mi++) {
#pragma unroll
        for (int ni = 0; ni < 2; ni++) {
            int col = nc0 + ni * 16 + lrow;
#pragma unroll
            for (int rr = 0; rr < 4; rr++) {
                int row = mi * 16 + lk * 4 + rr;
                float val = sp_(acc[mi][ni][rr] + b1v[ni]);
                *(short*)((char*)ht + row * 256 + ((col * 2) ^ ((row & 7) << 4))) = bfb(val);
            }
        }
    }
    __syncthreads();

    // GEMM2: [64x128] @ [128x64], each wave owns 16 output cols
    f32x4 acc2[4];
#pragma unroll
    for (int mi = 0; mi < 4; mi++) acc2[mi] = (f32x4){0.f, 0.f, 0.f, 0.f};
#pragma unroll
    for (int ks = 0; ks < 4; ks++) {
        int kb = ks * 64 + lk * 16;
        short8 av[4];
#pragma unroll
        for (int mi = 0; mi < 4; mi++) {
            int row = mi * 16 + lrow;
            av[mi] = *(const short8*)((const char*)ht + row * 256 + (kb ^ ((row & 7) << 4)));
        }
#pragma unroll
        for (int mi = 0; mi < 4; mi++)
            acc2[mi] = __builtin_amdgcn_mfma_f32_16x16x32_bf16(av[mi], w2f[ks], acc2[mi], 0, 0, 0);
    }
    // epilogue: +b2 +x residual, write y, BN partial sums
    float s1 = 0.f, s2 = 0.f;
#pragma unroll
    for (int mi = 0; mi < 4; mi++) {
#pragma unroll
        for (int rr = 0; rr < 4; rr++) {
            int row = mi * 16 + lk * 4 + rr;
            int node = n0 + row;
            if (node < N_NODES) {
                float v = acc2[mi][rr] + b2v + xf[(size_t)node * DIM + col2];
                y[(size_t)node * DIM + col2] = v;
                s1 += v;
                s2 += v * v;
            }
        }
    }
    s1 += __shfl_xor(s1, 16); s1 += __shfl_xor(s1, 32);
    s2 += __shfl_xor(s2, 16); s2 += __shfl_xor(s2, 32);
    if (lane < 16) {
        atomicAdd(&stats[col2], s1);
        atomicAdd(&stats[64 + col2], s2);
    }
}

// ---------------------------------------------------------------- BN finalize: a=gamma*rstd, b=beta-mu*a
__global__ void k_bnfin(const float* __restrict__ gamma, const float* __restrict__ beta,
                        float* __restrict__ stats) {
    int d = threadIdx.x;
    float mu = stats[d] * (1.f / N_NODES);
    float var = stats[64 + d] * (1.f / N_NODES) - mu * mu;
    float rstd = rsqrtf(var + BN_EPS);
    float a = gamma[d] * rstd;
    stats[128 + d] = a;
    stats[192 + d] = beta[d] - mu * a;
}

// ---------------------------------------------------------------- BN apply -> new x (f32 + bf16)
__global__ void k_bnapply(const float* __restrict__ y, const float* __restrict__ stats,
                          float* __restrict__ x, __hip_bfloat16* __restrict__ xb) {
    int idx = (blockIdx.x * 256 + threadIdx.x) * 4;
    if (idx >= N_NODES * DIM) return;
    int d = idx & 63;
    float4 v = *(const float4*)(y + idx);
    float4 r;
    r.x = stats[128 + d + 0] * v.x + stats[192 + d + 0];
    r.y = stats[128 + d + 1] * v.y + stats[192 + d + 1];
    r.z = stats[128 + d + 2] * v.z + stats[192 + d + 2];
    r.w = stats[128 + d + 3] * v.w + stats[192 + d + 3];
    *(float4*)(x + idx) = r;
    short4v s = {bfb(r.x), bfb(r.y), bfb(r.z), bfb(r.w)};
    *(short4v*)((char*)(xb + idx)) = s;
}

// ---------------------------------------------------------------- pool (atomic mean prep)
__global__ void k_pool(const int* __restrict__ batch, const float* __restrict__ x,
                       float* __restrict__ psum, float* __restrict__ pcnt) {
    int t = threadIdx.x;
    int nloc = t >> 6, d = t & 63;
    int node = blockIdx.x * 4 + nloc;
    if (node >= N_NODES) return;
    int g = batch[node];
    atomicAdd(&psum[g * 64 + d], x[(size_t)node * 64 + d]);
    if (d == 0) atomicAdd(&pcnt[g], 1.f);
}

// ---------------------------------------------------------------- output MLP (f32)
__global__ void k_out(const float* __restrict__ psum, const float* __restrict__ pcnt,
                      const float* __restrict__ W1, const float* __restrict__ b1,
                      const float* __restrict__ W2, const float* __restrict__ b2,
                      float* __restrict__ out) {
    __shared__ float pl[64];
    __shared__ float wsum[2];
    int g = blockIdx.x, t = threadIdx.x;
    if (t < 64) pl[t] = psum[g * 64 + t] / fmaxf(pcnt[g], 1.f);
    __syncthreads();
    float a = b1[t];
#pragma unroll
    for (int d = 0; d < 64; d++) a += pl[d] * W1[d * 128 + t];
    float c = sp_(a) * W2[t];
#pragma unroll
    for (int off = 32; off >= 1; off >>= 1) c += __shfl_down(c, off);
    int lane = t & 63, wid = t >> 6;
    if (lane == 0) wsum[wid] = c;
    __syncthreads();
    if (t == 0) out[g] = wsum[0] + wsum[1] + b2[0];
}

// ---------------------------------------------------------------- launch
extern "C" void kernel_launch(void* const* d_in, const int* in_sizes, int n_in,
                              void* d_out, int out_size, void* d_ws, size_t ws_size,
                              hipStream_t stream) {
    const int*   az    = (const int*)d_in[0];
    const int*   ei    = (const int*)d_in[1];
    const float* eattr = (const float*)d_in[2];
    const int*   batch = (const int*)d_in[3];
    const float* emb   = (const float*)d_in[4];
    const float* eW1   = (const float*)d_in[5];
    const float* eb1   = (const float*)d_in[6];
    const float* eW2   = (const float*)d_in[7];
    const float* eb2   = (const float*)d_in[8];
    const float* nW1   = (const float*)d_in[9];
    const float* nb1   = (const float*)d_in[10];
    const float* nW2   = (const float*)d_in[11];
    const float* nb2   = (const float*)d_in[12];
    const float* gam   = (const float*)d_in[13];
    const float* bet   = (const float*)d_in[14];
    const float* oW1   = (const float*)d_in[15];
    const float* ob1   = (const float*)d_in[16];
    const float* oW2   = (const float*)d_in[17];
    const float* ob2   = (const float*)d_in[18];
    const int* esrc = ei;
    const int* edst = ei + N_EDGES;

    float* x     = (float*)d_ws;
    float* y     = x + (size_t)N_NODES * DIM;
    float* aggr  = y + (size_t)N_NODES * DIM;
    float* stats = aggr + (size_t)N_NODES * HID;     // 256 floats (adjacent: joint memset)
    float* psum  = stats + 256;
    float* pcnt  = psum + NGRAPH * 64;
    __hip_bfloat16* xb = (__hip_bfloat16*)(pcnt + NGRAPH);
    short* ew1T = (short*)(xb + (size_t)N_NODES * DIM);   // [3][128][128]
    short* ew2T = ew1T + 3 * 128 * 128;                   // [3][128][128]
    short* nw1T = ew2T + 3 * 128 * 128;                   // [3][128][192]
    short* nw2T = nw1T + 3 * 128 * 192;                   // [3][64][128]
    int*   cursor = (int*)(nw2T + 3 * 64 * 128);          // [50000]
    int*   ssrc   = cursor + N_NODES;                     // [800000]
    int*   sdstA  = ssrc + N_EDGES;                       // [800000]
    float* sattr  = (float*)(sdstA + N_EDGES);            // [800000]

    k_embed<<<(N_NODES * DIM + 255) / 256, 256, 0, stream>>>(az, emb, x, xb);

    // pre-transpose all layer weights to bf16 [n][k]
    k_wprep<<<dim3(64, 3), 256, 0, stream>>>(eW1, ew1T, 128 * 128, 7, 129 * 128);
    k_wprep<<<dim3(64, 3), 256, 0, stream>>>(eW2, ew2T, 128 * 128, 7, 128 * 128);
    k_wprep<<<dim3(96, 3), 256, 0, stream>>>(nW1, nw1T, 192 * 128, 7, 192 * 128);
    k_wprep<<<dim3(32, 3), 256, 0, stream>>>(nW2, nw2T, 128 * 64, 6, 128 * 64);

    // counting sort of edges by dst (once per launch; reused by all 3 layers)
    hipMemsetAsync(cursor, 0, N_NODES * sizeof(int), stream);
    k_hist<<<(N_EDGES + 255) / 256, 256, 0, stream>>>(edst, cursor);
    k_scan<<<1, 1024, 0, stream>>>(cursor, cursor);   // in-place: per-thread own-index RMW
    k_scatter<<<(N_EDGES + 255) / 256, 256, 0, stream>>>(esrc, edst, eattr, cursor,
                                                         ssrc, sdstA, sattr);

    for (int l = 0; l < 3; l++) {
        hipMemsetAsync(aggr, 0, ((size_t)N_NODES * HID + 256) * sizeof(float), stream);
        k_edge<<<500, 512, 0, stream>>>(xb, ssrc, sdstA, sattr,
                                        eW1 + (size_t)l * 129 * 128, eb1 + l * 128, eb2 + l * 128,
                                        ew1T + (size_t)l * 128 * 128, ew2T + (size_t)l * 128 * 128,
                                        aggr);
        k_node<<<(N_NODES + 63) / 64, 256, 0, stream>>>(xb, x, aggr,
                                                        nw1T + (size_t)l * 128 * 192, nb1 + l * 128,
                                                        nw2T + (size_t)l * 64 * 128, nb2 + l * 64,
                                                        y, stats);
        k_bnfin<<<1, 64, 0, stream>>>(gam + l * 64, bet + l * 64, stats);
        k_bnapply<<<(N_NODES * DIM / 4 + 255) / 256, 256, 0, stream>>>(y, stats, x, xb);
    }

    hipMemsetAsync(psum, 0, (NGRAPH * 64 + NGRAPH) * sizeof(float), stream);
    k_pool<<<(N_NODES + 3) / 4, 256, 0, stream>>>(batch, x, psum, pcnt);
    k_out<<<NGRAPH, 128, 0, stream>>>(psum, pcnt, oW1, ob1, oW2, ob2, (float*)d_out);
}

// Round 7
// 1037.100 us; speedup vs baseline: 3.2796x; 1.2524x over previous
//
#include <hip/hip_runtime.h>
#include <hip/hip_bf16.h>

#define N_NODES 50000
#define N_EDGES 800000
#define DIM 64
#define HID 128
#define NGRAPH 128
#define BN_EPS 1e-5f

typedef __attribute__((ext_vector_type(8))) short short8;
typedef __attribute__((ext_vector_type(4))) short short4v;
typedef __attribute__((ext_vector_type(4))) float f32x4;
typedef __attribute__((ext_vector_type(4))) int int4v;

__device__ __forceinline__ float sp_(float v) {
    // softplus via hardware v_exp_f32 / v_log_f32 (~1e-6 abs err, fine at bf16)
    return fmaxf(v, 0.f) + __logf(1.f + __expf(-fabsf(v)));
}
__device__ __forceinline__ short bfb(float f) {
    __hip_bfloat16 h = __float2bfloat16(f);
    return __builtin_bit_cast(short, h);
}
__device__ __forceinline__ float b2f(short s) {
    unsigned u = ((unsigned)(unsigned short)s) << 16;
    return __builtin_bit_cast(float, u);
}

// ---------------------------------------------------------------- embed
__global__ void k_embed(const int* __restrict__ az, const float* __restrict__ emb,
                        float* __restrict__ x, __hip_bfloat16* __restrict__ xb) {
    int idx = blockIdx.x * 256 + threadIdx.x;
    if (idx >= N_NODES * DIM) return;
    int n = idx >> 6;
    int d = idx & 63;
    float v = emb[az[n] * DIM + d];
    x[idx] = v;
    xb[idx] = __float2bfloat16(v);
}

// ---------------------------------------------------------------- weight prep:
// transpose f32 [K][N] (row-major) -> bf16 [N][K]; blockIdx.y = layer
__global__ void k_wprep(const float* __restrict__ src, short* __restrict__ dst,
                        int total, int nshift, int srcStride) {
    int l = blockIdx.y;
    int idx = blockIdx.x * 256 + threadIdx.x;
    if (idx >= total) return;
    int K = total >> nshift;
    int k = idx >> nshift;
    int n = idx & ((1 << nshift) - 1);
    dst[(size_t)l * total + n * K + k] = bfb(src[(size_t)l * srcStride + idx]);
}

// ---------------------------------------------------------------- counting sort by dst
__global__ void k_hist(const int* __restrict__ edst, int* __restrict__ deg) {
    int e = blockIdx.x * 256 + threadIdx.x;
    if (e < N_EDGES) atomicAdd(&deg[edst[e]], 1);
}

// single block, 1024 threads: exclusive prefix sum deg -> cursor
__global__ void k_scan(const int* __restrict__ deg, int* __restrict__ cursor) {
    __shared__ int wsum[16];
    __shared__ int carry;
    const int t = threadIdx.x, lane = t & 63, w = t >> 6;
    if (t == 0) carry = 0;
    __syncthreads();
    for (int base = 0; base < N_NODES; base += 1024) {
        int i = base + t;
        int v = (i < N_NODES) ? deg[i] : 0;
        int s = v;
#pragma unroll
        for (int off = 1; off < 64; off <<= 1) {
            int u = __shfl_up(s, off);
            if (lane >= off) s += u;
        }
        if (lane == 63) wsum[w] = s;
        __syncthreads();
        if (w == 0) {
            int ws = (lane < 16) ? wsum[lane] : 0;
#pragma unroll
            for (int off = 1; off < 16; off <<= 1) {
                int u = __shfl_up(ws, off);
                if (lane >= off) ws += u;
            }
            if (lane < 16) wsum[lane] = ws;
        }
        __syncthreads();
        int woff = (w == 0) ? 0 : wsum[w - 1];
        int excl = carry + woff + s - v;
        if (i < N_NODES) cursor[i] = excl;
        __syncthreads();
        if (t == 1023) carry += wsum[15];
        __syncthreads();
    }
}

__global__ void k_scatter(const int* __restrict__ esrc, const int* __restrict__ edst,
                          const float* __restrict__ eattr, int* __restrict__ cursor,
                          int* __restrict__ ssrc, int* __restrict__ sdst,
                          float* __restrict__ sattr) {
    int e = blockIdx.x * 256 + threadIdx.x;
    if (e >= N_EDGES) return;
    int d = edst[e];
    int pos = atomicAdd(&cursor[d], 1);
    ssrc[pos] = esrc[e];
    sdst[pos] = d;
    sattr[pos] = eattr[e];
}

// ---------------------------------------------------------------- graph bounds:
// batch is sorted; gstart[g] = lower_bound(batch, g), g in [0,128]
__global__ void k_gbounds(const int* __restrict__ batch, int* __restrict__ gstart) {
    int g = threadIdx.x;
    if (g > NGRAPH) return;
    int lo = 0, hi = N_NODES;
    while (lo < hi) {
        int mid = (lo + hi) >> 1;
        if (batch[mid] < g) lo = mid + 1; else hi = mid;
    }
    gstart[g] = lo;
}

// ---------------------------------------------------------------- edge MLP (dst-sorted edges)
// 512 threads / 8 waves, 16 output cols per wave -> weight frags fit in regs
// (32 VGPR weights + 32 AGPR acc, no spill at 4 waves/SIMD). Contiguous
// 25-tile chunk per block for dst-gather L1 locality. Epilogue: bf16 m-tile
// in LDS, per-segment reduce, one atomicAdd per (segment, col).
__launch_bounds__(512, 4)
__global__ void k_edge(const __hip_bfloat16* __restrict__ xb,
                       const int* __restrict__ ssrc, const int* __restrict__ sdst,
                       const float* __restrict__ sattr,
                       const float* __restrict__ W1f, const float* __restrict__ b1,
                       const float* __restrict__ b2,
                       const short* __restrict__ w1T, const short* __restrict__ w2T,
                       float* __restrict__ aggr) {
    __shared__ short zt[64 * 128];     // 16KB; phase2: reused as bf16 m-tile
    __shared__ short ht[64 * 128];     // 16KB
    __shared__ float attr_s[64];
    __shared__ int   dst_s[64];
    __shared__ int   seg_start[65];
    __shared__ int   seg_dst[64];
    __shared__ int   nseg_s;

    const int t = threadIdx.x;
    const int wid = t >> 6, lane = t & 63;
    const int lrow = lane & 15, lk = lane >> 4;
    const int r = t >> 3, q = t & 7;          // staging: 8 threads per edge row
    const int col = wid * 16 + lrow;          // this thread's output column

    // preload weight fragments + per-col scalars into registers (16 cols/wave)
    short8 w1f[4], w2f[4];
#pragma unroll
    for (int ks = 0; ks < 4; ks++) {
        int kb = ks * 64 + lk * 16;
        w1f[ks] = *(const short8*)((const char*)w1T + col * 256 + kb);
        w2f[ks] = *(const short8*)((const char*)w2T + col * 256 + kb);
    }
    const float b1v = b1[col];
    const float b2v = b2[col];
    const float wlv = W1f[128 * 128 + col];   // attr rank-1 row (f32 original)

    const int NT = N_EDGES / 64;              // 12500
    const int tile0 = blockIdx.x * 25;
    const int tile1 = (tile0 + 25 < NT) ? tile0 + 25 : NT;

    for (int tile = tile0; tile < tile1; ++tile) {
        const int e0 = tile * 64;
        // ---- stage z tile: cols 0..63 = x[dst], 64..127 = x[src]; 32B/thread
        {
            int e = e0 + r;
            int dn = sdst[e], sn = ssrc[e];
            if (q == 0) { dst_s[r] = dn; attr_s[r] = sattr[e]; }
            int node = (q < 4) ? dn : sn;
            const __hip_bfloat16* xr = xb + (size_t)node * DIM + (q & 3) * 16;
            int4v v0 = *(const int4v*)(xr);
            int4v v1 = *(const int4v*)(xr + 8);
            int cb = (q >> 2) * 128 + (q & 3) * 32;
            *(int4v*)((char*)zt + r * 256 + (cb ^ ((r & 7) << 4))) = v0;
            *(int4v*)((char*)zt + r * 256 + ((cb + 16) ^ ((r & 7) << 4))) = v1;
        }
        __syncthreads();                       // A: z tile + dst_s ready

        // ---- segment list (wave 0): boundaries where sorted dst changes
        if (wid == 0) {
            int d = dst_s[lane];
            int prev = (lane == 0) ? -1 : dst_s[lane - 1];
            bool start = (d != prev);
            unsigned long long mask = __ballot(start);
            int sidx = __popcll(mask & ((1ull << lane) - 1));
            if (start) { seg_start[sidx] = lane; seg_dst[sidx] = d; }
            if (lane == 63) {
                int ns = __popcll(mask);
                nseg_s = ns;
                seg_start[ns] = 64;
            }
        }

        // ---- GEMM1: [64x128] @ [128x128], wave owns 16 cols
        f32x4 acc[4];
#pragma unroll
        for (int mi = 0; mi < 4; mi++) acc[mi] = (f32x4){0.f, 0.f, 0.f, 0.f};
#pragma unroll
        for (int ks = 0; ks < 4; ks++) {
            int kb = ks * 64 + lk * 16;
            short8 av[4];
#pragma unroll
            for (int mi = 0; mi < 4; mi++) {
                int row = mi * 16 + lrow;
                av[mi] = *(const short8*)((const char*)zt + row * 256 + (kb ^ ((row & 7) << 4)));
            }
#pragma unroll
            for (int mi = 0; mi < 4; mi++)
                acc[mi] = __builtin_amdgcn_mfma_f32_16x16x32_bf16(av[mi], w1f[ks], acc[mi], 0, 0, 0);
        }
        // epilogue 1: + b1 + attr * W1_lastrow, softplus, -> ht (bf16)
#pragma unroll
        for (int mi = 0; mi < 4; mi++) {
#pragma unroll
            for (int rr = 0; rr < 4; rr++) {
                int row = mi * 16 + lk * 4 + rr;
                float val = acc[mi][rr] + b1v + attr_s[row] * wlv;
                *(short*)((char*)ht + row * 256 + ((col * 2) ^ ((row & 7) << 4))) = bfb(sp_(val));
            }
        }
        __syncthreads();                       // B: all zt reads done, ht ready

        // ---- GEMM2: [64x128] @ [128x128]
        f32x4 acc2[4];
#pragma unroll
        for (int mi = 0; mi < 4; mi++) acc2[mi] = (f32x4){0.f, 0.f, 0.f, 0.f};
#pragma unroll
        for (int ks = 0; ks < 4; ks++) {
            int kb = ks * 64 + lk * 16;
            short8 av[4];
#pragma unroll
            for (int mi = 0; mi < 4; mi++) {
                int row = mi * 16 + lrow;
                av[mi] = *(const short8*)((const char*)ht + row * 256 + (kb ^ ((row & 7) << 4)));
            }
#pragma unroll
            for (int mi = 0; mi < 4; mi++)
                acc2[mi] = __builtin_amdgcn_mfma_f32_16x16x32_bf16(av[mi], w2f[ks], acc2[mi], 0, 0, 0);
        }
        // epilogue 2: softplus(+b2) -> m-tile in LDS (bf16, reuses zt)
#pragma unroll
        for (int mi = 0; mi < 4; mi++) {
#pragma unroll
            for (int rr = 0; rr < 4; rr++) {
                int row = mi * 16 + lk * 4 + rr;
                float val = sp_(acc2[mi][rr] + b2v);
                *(short*)((char*)zt + row * 256 + ((col * 2) ^ ((row & 7) << 4))) = bfb(val);
            }
        }
        __syncthreads();                       // C: m-tile visible to all

        // ---- per-segment reduce + one atomicAdd per (segment, col)
        {
            int nseg = nseg_s;
            int rcol = t & 127, h = t >> 7;    // 4 thread-groups over segments
            for (int s = h; s < nseg; s += 4) {
                int r0 = seg_start[s], r1 = seg_start[s + 1];
                float sum = 0.f;
                for (int rr = r0; rr < r1; rr++)
                    sum += b2f(*(const short*)((const char*)zt + rr * 256 + ((rcol * 2) ^ ((rr & 7) << 4))));
                atomicAdd(&aggr[(size_t)seg_dst[s] * HID + rcol], sum);
            }
        }
        __syncthreads();                       // D: reduce done, zt/seg reusable
    }
}

// ---------------------------------------------------------------- node MLP + BN partial stats
// tile = 64 nodes, K=192 (x||aggr) -> H=128 -> sp -> K=128 -> D=64, +x residual
__launch_bounds__(256, 3)
__global__ void k_node(const __hip_bfloat16* __restrict__ xb,
                       const float* __restrict__ xf,
                       const float* __restrict__ aggr,
                       const short* __restrict__ w1T, const float* __restrict__ b1,
                       const short* __restrict__ w2T, const float* __restrict__ b2,
                       float* __restrict__ y, float* __restrict__ stats) {
    __shared__ short at[64 * 192];    // 24KB rowbytes 384
    __shared__ short ht[64 * 128];    // 16KB

    const int t = threadIdx.x;
    const int wid = t >> 6, lane = t & 63, lrow = lane & 15, lk = lane >> 4;
    const int n0 = blockIdx.x * 64;

    // preload weight fragments
    const int nc0 = wid * 32;
    short8 w1f[6][2];
    float b1v[2];
#pragma unroll
    for (int ni = 0; ni < 2; ni++) {
        int col = nc0 + ni * 16 + lrow;
#pragma unroll
        for (int ks = 0; ks < 6; ks++) {
            int kb = ks * 64 + lk * 16;
            w1f[ks][ni] = *(const short8*)((const char*)w1T + col * 384 + kb);
        }
        b1v[ni] = b1[col];
    }
    const int nc2 = wid * 16;
    const int col2 = nc2 + lrow;
    short8 w2f[4];
#pragma unroll
    for (int ks = 0; ks < 4; ks++)
        w2f[ks] = *(const short8*)((const char*)w2T + col2 * 256 + ks * 64 + lk * 16);
    const float b2v = b2[col2];

    // stage A rows: [x bf16 (64) || aggr f32->bf16 (128)]
    if (t < 64) {
        int node = n0 + t;
        if (node < N_NODES) {
            const __hip_bfloat16* xr = xb + (size_t)node * DIM;
#pragma unroll
            for (int i = 0; i < 8; i++) {
                int4v v = *(const int4v*)(xr + i * 8);
                *(int4v*)((char*)at + t * 384 + ((i * 16) ^ ((t & 7) << 4))) = v;
            }
        } else {
            int4v z = {0, 0, 0, 0};
#pragma unroll
            for (int i = 0; i < 8; i++)
                *(int4v*)((char*)at + t * 384 + ((i * 16) ^ ((t & 7) << 4))) = z;
        }
    }
    {
        int r = t >> 2, q = t & 3;
        int node = n0 + r;
#pragma unroll
        for (int i = 0; i < 4; i++) {
            short8 s = {0, 0, 0, 0, 0, 0, 0, 0};
            if (node < N_NODES) {
                const float* ar = aggr + (size_t)node * HID + q * 32 + i * 8;
                float4 f0 = *(const float4*)ar;
                float4 f1 = *(const float4*)(ar + 4);
                s = (short8){bfb(f0.x), bfb(f0.y), bfb(f0.z), bfb(f0.w),
                             bfb(f1.x), bfb(f1.y), bfb(f1.z), bfb(f1.w)};
            }
            int cb = 128 + q * 64 + i * 16;
            *(short8*)((char*)at + r * 384 + (cb ^ ((r & 7) << 4))) = s;
        }
    }
    __syncthreads();

    // GEMM1: [64x192] @ [192x128]
    f32x4 acc[4][2];
#pragma unroll
    for (int mi = 0; mi < 4; mi++)
#pragma unroll
        for (int ni = 0; ni < 2; ni++) acc[mi][ni] = (f32x4){0.f, 0.f, 0.f, 0.f};
#pragma unroll
    for (int ks = 0; ks < 6; ks++) {
        int kb = ks * 64 + lk * 16;
        short8 av[4];
#pragma unroll
        for (int mi = 0; mi < 4; mi++) {
            int row = mi * 16 + lrow;
            av[mi] = *(const short8*)((const char*)at + row * 384 + (kb ^ ((row & 7) << 4)));
        }
#pragma unroll
        for (int mi = 0; mi < 4; mi++)
#pragma unroll
            for (int ni = 0; ni < 2; ni++)
                acc[mi][ni] = __builtin_amdgcn_mfma_f32_16x16x32_bf16(av[mi], w1f[ks][ni], acc[mi][ni], 0, 0, 0);
    }
#pragma unroll
    for (int mi = 0; mi < 4; mi++) {
#pragma unroll
        for (int ni = 0; ni < 2; ni++) {
            int col = nc0 + ni * 16 + lrow;
#pragma unroll
            for (int rr = 0; rr < 4; rr++) {
                int row = mi * 16 + lk * 4 + rr;
                float val = sp_(acc[mi][ni][rr] + b1v[ni]);
                *(short*)((char*)ht + row * 256 + ((col * 2) ^ ((row & 7) << 4))) = bfb(val);
            }
        }
    }
    __syncthreads();

    // GEMM2: [64x128] @ [128x64], each wave owns 16 output cols
    f32x4 acc2[4];
#pragma unroll
    for (int mi = 0; mi < 4; mi++) acc2[mi] = (f32x4){0.f, 0.f, 0.f, 0.f};
#pragma unroll
    for (int ks = 0; ks < 4; ks++) {
        int kb = ks * 64 + lk * 16;
        short8 av[4];
#pragma unroll
        for (int mi = 0; mi < 4; mi++) {
            int row = mi * 16 + lrow;
            av[mi] = *(const short8*)((const char*)ht + row * 256 + (kb ^ ((row & 7) << 4)));
        }
#pragma unroll
        for (int mi = 0; mi < 4; mi++)
            acc2[mi] = __builtin_amdgcn_mfma_f32_16x16x32_bf16(av[mi], w2f[ks], acc2[mi], 0, 0, 0);
    }
    // epilogue: +b2 +x residual, write y, BN partial sums
    float s1 = 0.f, s2 = 0.f;
#pragma unroll
    for (int mi = 0; mi < 4; mi++) {
#pragma unroll
        for (int rr = 0; rr < 4; rr++) {
            int row = mi * 16 + lk * 4 + rr;
            int node = n0 + row;
            if (node < N_NODES) {
                float v = acc2[mi][rr] + b2v + xf[(size_t)node * DIM + col2];
                y[(size_t)node * DIM + col2] = v;
                s1 += v;
                s2 += v * v;
            }
        }
    }
    s1 += __shfl_xor(s1, 16); s1 += __shfl_xor(s1, 32);
    s2 += __shfl_xor(s2, 16); s2 += __shfl_xor(s2, 32);
    if (lane < 16) {
        atomicAdd(&stats[col2], s1);
        atomicAdd(&stats[64 + col2], s2);
    }
}

// ---------------------------------------------------------------- BN finalize: a=gamma*rstd, b=beta-mu*a
__global__ void k_bnfin(const float* __restrict__ gamma, const float* __restrict__ beta,
                        float* __restrict__ stats) {
    int d = threadIdx.x;
    float mu = stats[d] * (1.f / N_NODES);
    float var = stats[64 + d] * (1.f / N_NODES) - mu * mu;
    float rstd = rsqrtf(var + BN_EPS);
    float a = gamma[d] * rstd;
    stats[128 + d] = a;
    stats[192 + d] = beta[d] - mu * a;
}

// ---------------------------------------------------------------- BN apply -> new x (f32 + bf16)
__global__ void k_bnapply(const float* __restrict__ y, const float* __restrict__ stats,
                          float* __restrict__ x, __hip_bfloat16* __restrict__ xb) {
    int idx = (blockIdx.x * 256 + threadIdx.x) * 4;
    if (idx >= N_NODES * DIM) return;
    int d = idx & 63;
    float4 v = *(const float4*)(y + idx);
    float4 r;
    r.x = stats[128 + d + 0] * v.x + stats[192 + d + 0];
    r.y = stats[128 + d + 1] * v.y + stats[192 + d + 1];
    r.z = stats[128 + d + 2] * v.z + stats[192 + d + 2];
    r.w = stats[128 + d + 3] * v.w + stats[192 + d + 3];
    *(float4*)(x + idx) = r;
    short4v s = {bfb(r.x), bfb(r.y), bfb(r.z), bfb(r.w)};
    *(short4v*)((char*)(xb + idx)) = s;
}

// ---------------------------------------------------------------- pool: per-graph mean, no atomics
// one block per graph; batch sorted -> contiguous node range [gstart[g], gstart[g+1])
__global__ void k_pool2(const int* __restrict__ gstart, const float* __restrict__ x,
                        float* __restrict__ pooled) {
    __shared__ float red[256];
    const int g = blockIdx.x, t = threadIdx.x;
    const int d = t & 63, nl = t >> 6;
    const int s = gstart[g], e = gstart[g + 1];
    float sum = 0.f;
    for (int n = s + nl; n < e; n += 4)
        sum += x[(size_t)n * DIM + d];
    red[t] = sum;
    __syncthreads();
    if (t < 64) {
        float tot = red[t] + red[t + 64] + red[t + 128] + red[t + 192];
        int c = e - s;
        pooled[g * DIM + t] = tot / fmaxf((float)c, 1.f);
    }
}

// ---------------------------------------------------------------- output MLP (f32)
__global__ void k_out(const float* __restrict__ pooled,
                      const float* __restrict__ W1, const float* __restrict__ b1,
                      const float* __restrict__ W2, const float* __restrict__ b2,
                      float* __restrict__ out) {
    __shared__ float pl[64];
    __shared__ float wsum[2];
    int g = blockIdx.x, t = threadIdx.x;
    if (t < 64) pl[t] = pooled[g * 64 + t];
    __syncthreads();
    float a = b1[t];
#pragma unroll
    for (int d = 0; d < 64; d++) a += pl[d] * W1[d * 128 + t];
    float c = sp_(a) * W2[t];
#pragma unroll
    for (int off = 32; off >= 1; off >>= 1) c += __shfl_down(c, off);
    int lane = t & 63, wid = t >> 6;
    if (lane == 0) wsum[wid] = c;
    __syncthreads();
    if (t == 0) out[g] = wsum[0] + wsum[1] + b2[0];
}

// ---------------------------------------------------------------- launch
extern "C" void kernel_launch(void* const* d_in, const int* in_sizes, int n_in,
                              void* d_out, int out_size, void* d_ws, size_t ws_size,
                              hipStream_t stream) {
    const int*   az    = (const int*)d_in[0];
    const int*   ei    = (const int*)d_in[1];
    const float* eattr = (const float*)d_in[2];
    const int*   batch = (const int*)d_in[3];
    const float* emb   = (const float*)d_in[4];
    const float* eW1   = (const float*)d_in[5];
    const float* eb1   = (const float*)d_in[6];
    const float* eW2   = (const float*)d_in[7];
    const float* eb2   = (const float*)d_in[8];
    const float* nW1   = (const float*)d_in[9];
    const float* nb1   = (const float*)d_in[10];
    const float* nW2   = (const float*)d_in[11];
    const float* nb2   = (const float*)d_in[12];
    const float* gam   = (const float*)d_in[13];
    const float* bet   = (const float*)d_in[14];
    const float* oW1   = (const float*)d_in[15];
    const float* ob1   = (const float*)d_in[16];
    const float* oW2   = (const float*)d_in[17];
    const float* ob2   = (const float*)d_in[18];
    const int* esrc = ei;
    const int* edst = ei + N_EDGES;

    float* x     = (float*)d_ws;
    float* y     = x + (size_t)N_NODES * DIM;
    float* aggr  = y + (size_t)N_NODES * DIM;
    float* stats = aggr + (size_t)N_NODES * HID;     // 256 floats (adjacent: joint memset)
    float* pooled = stats + 256;                     // [128][64]
    __hip_bfloat16* xb = (__hip_bfloat16*)(pooled + NGRAPH * DIM);
    short* ew1T = (short*)(xb + (size_t)N_NODES * DIM);   // [3][128][128]
    short* ew2T = ew1T + 3 * 128 * 128;                   // [3][128][128]
    short* nw1T = ew2T + 3 * 128 * 128;                   // [3][128][192]
    short* nw2T = nw1T + 3 * 128 * 192;                   // [3][64][128]
    int*   cursor = (int*)(nw2T + 3 * 64 * 128);          // [50000]
    int*   ssrc   = cursor + N_NODES;                     // [800000]
    int*   sdstA  = ssrc + N_EDGES;                       // [800000]
    float* sattr  = (float*)(sdstA + N_EDGES);            // [800000]
    int*   gstart = (int*)(sattr + N_EDGES);              // [129]

    k_embed<<<(N_NODES * DIM + 255) / 256, 256, 0, stream>>>(az, emb, x, xb);

    // pre-transpose all layer weights to bf16 [n][k]
    k_wprep<<<dim3(64, 3), 256, 0, stream>>>(eW1, ew1T, 128 * 128, 7, 129 * 128);
    k_wprep<<<dim3(64, 3), 256, 0, stream>>>(eW2, ew2T, 128 * 128, 7, 128 * 128);
    k_wprep<<<dim3(96, 3), 256, 0, stream>>>(nW1, nw1T, 192 * 128, 7, 192 * 128);
    k_wprep<<<dim3(32, 3), 256, 0, stream>>>(nW2, nw2T, 128 * 64, 6, 128 * 64);

    // counting sort of edges by dst (once per launch; reused by all 3 layers)
    hipMemsetAsync(cursor, 0, N_NODES * sizeof(int), stream);
    k_hist<<<(N_EDGES + 255) / 256, 256, 0, stream>>>(edst, cursor);
    k_scan<<<1, 1024, 0, stream>>>(cursor, cursor);   // in-place: per-thread own-index RMW
    k_scatter<<<(N_EDGES + 255) / 256, 256, 0, stream>>>(esrc, edst, eattr, cursor,
                                                         ssrc, sdstA, sattr);
    // graph node ranges (batch sorted)
    k_gbounds<<<1, 256, 0, stream>>>(batch, gstart);

    for (int l = 0; l < 3; l++) {
        hipMemsetAsync(aggr, 0, ((size_t)N_NODES * HID + 256) * sizeof(float), stream);
        k_edge<<<500, 512, 0, stream>>>(xb, ssrc, sdstA, sattr,
                                        eW1 + (size_t)l * 129 * 128, eb1 + l * 128, eb2 + l * 128,
                                        ew1T + (size_t)l * 128 * 128, ew2T + (size_t)l * 128 * 128,
                                        aggr);
        k_node<<<(N_NODES + 63) / 64, 256, 0, stream>>>(xb, x, aggr,
                                                        nw1T + (size_t)l * 128 * 192, nb1 + l * 128,
                                                        nw2T + (size_t)l * 64 * 128, nb2 + l * 64,
                                                        y, stats);
        k_bnfin<<<1, 64, 0, stream>>>(gam + l * 64, bet + l * 64, stats);
        k_bnapply<<<(N_NODES * DIM / 4 + 255) / 256, 256, 0, stream>>>(y, stats, x, xb);
    }

    k_pool2<<<NGRAPH, 256, 0, stream>>>(gstart, x, pooled);
    k_out<<<NGRAPH, 128, 0, stream>>>(pooled, oW1, ob1, oW2, ob2, (float*)d_out);
}

// Round 10
// 977.498 us; speedup vs baseline: 3.4796x; 1.0610x over previous
//
#include <hip/hip_runtime.h>
#include <hip/hip_bf16.h>

#define N_NODES 50000
#define N_EDGES 800000
#define DIM 64
#define HID 128
#define NGRAPH 128
#define BN_EPS 1e-5f

typedef __attribute__((ext_vector_type(8))) short short8;
typedef __attribute__((ext_vector_type(4))) short short4v;
typedef __attribute__((ext_vector_type(4))) float f32x4;
typedef __attribute__((ext_vector_type(4))) int int4v;

__device__ __forceinline__ float sp_(float v) {
    // softplus via hardware v_exp_f32 / v_log_f32 (~1e-6 abs err, fine at bf16)
    return fmaxf(v, 0.f) + __logf(1.f + __expf(-fabsf(v)));
}
__device__ __forceinline__ short bfb(float f) {
    __hip_bfloat16 h = __float2bfloat16(f);
    return __builtin_bit_cast(short, h);
}
__device__ __forceinline__ float b2f(short s) {
    unsigned u = ((unsigned)(unsigned short)s) << 16;
    return __builtin_bit_cast(float, u);
}

// ---------------------------------------------------------------- embed
__global__ void k_embed(const int* __restrict__ az, const float* __restrict__ emb,
                        float* __restrict__ x, __hip_bfloat16* __restrict__ xb) {
    int idx = blockIdx.x * 256 + threadIdx.x;
    if (idx >= N_NODES * DIM) return;
    int n = idx >> 6;
    int d = idx & 63;
    float v = emb[az[n] * DIM + d];
    x[idx] = v;
    xb[idx] = __float2bfloat16(v);
}

// ---------------------------------------------------------------- weight prep:
// transpose f32 [K][N] (row-major) -> bf16 [N][K]; blockIdx.y = layer
__global__ void k_wprep(const float* __restrict__ src, short* __restrict__ dst,
                        int total, int nshift, int srcStride) {
    int l = blockIdx.y;
    int idx = blockIdx.x * 256 + threadIdx.x;
    if (idx >= total) return;
    int K = total >> nshift;
    int k = idx >> nshift;
    int n = idx & ((1 << nshift) - 1);
    dst[(size_t)l * total + n * K + k] = bfb(src[(size_t)l * srcStride + idx]);
}

// ---------------------------------------------------------------- counting sort by dst
__global__ void k_hist(const int* __restrict__ edst, int* __restrict__ deg) {
    int e = blockIdx.x * 256 + threadIdx.x;
    if (e < N_EDGES) atomicAdd(&deg[edst[e]], 1);
}

// single block, 1024 threads: exclusive prefix sum deg -> cursor
__global__ void k_scan(const int* __restrict__ deg, int* __restrict__ cursor) {
    __shared__ int wsum[16];
    __shared__ int carry;
    const int t = threadIdx.x, lane = t & 63, w = t >> 6;
    if (t == 0) carry = 0;
    __syncthreads();
    for (int base = 0; base < N_NODES; base += 1024) {
        int i = base + t;
        int v = (i < N_NODES) ? deg[i] : 0;
        int s = v;
#pragma unroll
        for (int off = 1; off < 64; off <<= 1) {
            int u = __shfl_up(s, off);
            if (lane >= off) s += u;
        }
        if (lane == 63) wsum[w] = s;
        __syncthreads();
        if (w == 0) {
            int ws = (lane < 16) ? wsum[lane] : 0;
#pragma unroll
            for (int off = 1; off < 16; off <<= 1) {
                int u = __shfl_up(ws, off);
                if (lane >= off) ws += u;
            }
            if (lane < 16) wsum[lane] = ws;
        }
        __syncthreads();
        int woff = (w == 0) ? 0 : wsum[w - 1];
        int excl = carry + woff + s - v;
        if (i < N_NODES) cursor[i] = excl;
        __syncthreads();
        if (t == 1023) carry += wsum[15];
        __syncthreads();
    }
}

__global__ void k_scatter(const int* __restrict__ esrc, const int* __restrict__ edst,
                          const float* __restrict__ eattr, int* __restrict__ cursor,
                          int* __restrict__ ssrc, int* __restrict__ sdst,
                          float* __restrict__ sattr) {
    int e = blockIdx.x * 256 + threadIdx.x;
    if (e >= N_EDGES) return;
    int d = edst[e];
    int pos = atomicAdd(&cursor[d], 1);
    ssrc[pos] = esrc[e];
    sdst[pos] = d;
    sattr[pos] = eattr[e];
}

// ---------------------------------------------------------------- graph bounds
__global__ void k_gbounds(const int* __restrict__ batch, int* __restrict__ gstart) {
    int g = threadIdx.x;
    if (g > NGRAPH) return;
    int lo = 0, hi = N_NODES;
    while (lo < hi) {
        int mid = (lo + hi) >> 1;
        if (batch[mid] < g) lo = mid + 1; else hi = mid;
    }
    gstart[g] = lo;
}

// ---------------------------------------------------------------- per-node A/B:
// A[n] = x[n]@W1[0:64] + b1 (dst half), B[n] = x[n]@W1[64:128] (src half)
// output xab[n][0:128]=A bf16, [128:256]=B bf16
__launch_bounds__(512, 2)
__global__ void k_ab(const __hip_bfloat16* __restrict__ xb,
                     const short* __restrict__ w1T, const float* __restrict__ b1,
                     short* __restrict__ xab) {
    __shared__ short xt[64 * 64];     // 8KB, rowbytes 128
    __shared__ short ot[64 * 256];    // 32KB, rowbytes 512
    const int t = threadIdx.x;
    const int wid = t >> 6, lane = t & 63, lrow = lane & 15, lk = lane >> 4;
    const int col = wid * 16 + lrow;
    const int n0 = blockIdx.x * 64;

    short8 wa[2], wb[2];
#pragma unroll
    for (int ks = 0; ks < 2; ks++) {
        wa[ks] = *(const short8*)((const char*)w1T + col * 256 + ks * 64 + lk * 16);
        wb[ks] = *(const short8*)((const char*)w1T + col * 256 + 128 + ks * 64 + lk * 16);
    }
    const float b1v = b1[col];

    {   // stage x tile
        int r = t >> 3, q = t & 7;
        int node = n0 + r;
        int4v v = {0, 0, 0, 0};
        if (node < N_NODES) v = *(const int4v*)(xb + (size_t)node * DIM + q * 8);
        *(int4v*)((char*)xt + r * 128 + ((q * 16) ^ ((r & 7) << 4))) = v;
    }
    __syncthreads();

    f32x4 aa[4], ab[4];
#pragma unroll
    for (int mi = 0; mi < 4; mi++) { aa[mi] = (f32x4){0.f,0.f,0.f,0.f}; ab[mi] = (f32x4){0.f,0.f,0.f,0.f}; }
#pragma unroll
    for (int ks = 0; ks < 2; ks++) {
        int kb = ks * 64 + lk * 16;
        short8 av[4];
#pragma unroll
        for (int mi = 0; mi < 4; mi++) {
            int row = mi * 16 + lrow;
            av[mi] = *(const short8*)((const char*)xt + row * 128 + (kb ^ ((row & 7) << 4)));
        }
#pragma unroll
        for (int mi = 0; mi < 4; mi++) {
            aa[mi] = __builtin_amdgcn_mfma_f32_16x16x32_bf16(av[mi], wa[ks], aa[mi], 0, 0, 0);
            ab[mi] = __builtin_amdgcn_mfma_f32_16x16x32_bf16(av[mi], wb[ks], ab[mi], 0, 0, 0);
        }
    }
#pragma unroll
    for (int mi = 0; mi < 4; mi++) {
#pragma unroll
        for (int rr = 0; rr < 4; rr++) {
            int row = mi * 16 + lk * 4 + rr;
            int swz = (row & 7) << 4;
            *(short*)((char*)ot + row * 512 + ((col * 2) ^ swz)) = bfb(aa[mi][rr] + b1v);
            *(short*)((char*)ot + row * 512 + 256 + ((col * 2) ^ swz)) = bfb(ab[mi][rr]);
        }
    }
    __syncthreads();
    // coalesced LDS -> global copy (unswizzle)
#pragma unroll
    for (int it = 0; it < 4; it++) {
        int idx = it * 8192 + t * 16;
        int row = idx >> 9, off = idx & 511;
        int node = n0 + row;
        if (node < N_NODES) {
            int base = off & 256, lo = off & 255;
            int4v v = *(const int4v*)((char*)ot + row * 512 + base + (lo ^ ((row & 7) << 4)));
            *(int4v*)((char*)xab + (size_t)node * 512 + off) = v;
        }
    }
}

// ---------------------------------------------------------------- edge MLP (dst-sorted, A/B precomputed)
// per edge: h = sp(A[dst]+B[src]+attr*wl) (staging) -> GEMM2 -> sp -> segment reduce
__launch_bounds__(512, 4)
__global__ void k_edge(const short* __restrict__ xab,
                       const int* __restrict__ ssrc, const int* __restrict__ sdst,
                       const float* __restrict__ sattr,
                       const float* __restrict__ wl, const float* __restrict__ b2,
                       const short* __restrict__ w2T,
                       float* __restrict__ aggr) {
    __shared__ short ht[64 * 128];     // 16KB bf16 h-tile, rowbytes 256
    __shared__ float mt[64 * 128];     // 32KB f32 m-tile, rowbytes 512
    __shared__ int   dst_s[64];
    __shared__ int   seg_start[65];
    __shared__ int   seg_dst[64];
    __shared__ int   nseg_s;

    const int t = threadIdx.x;
    const int wid = t >> 6, lane = t & 63;
    const int lrow = lane & 15, lk = lane >> 4;
    const int r = t >> 3, q = t & 7;          // staging: 8 threads per edge row
    const int col = wid * 16 + lrow;          // GEMM output column

    short8 w2f[4];
#pragma unroll
    for (int ks = 0; ks < 4; ks++)
        w2f[ks] = *(const short8*)((const char*)w2T + col * 256 + ks * 64 + lk * 16);
    const float b2v = b2[col];
    float wlv[16];
#pragma unroll
    for (int i = 0; i < 16; i++) wlv[i] = wl[q * 16 + i];

    const int NT = N_EDGES / 64;              // 12500
    const int tile0 = blockIdx.x * 25;
    const int tile1 = (tile0 + 25 < NT) ? tile0 + 25 : NT;

    for (int tile = tile0; tile < tile1; ++tile) {
        const int e0 = tile * 64;
        // ---- stage h tile: h = sp(A[dst] + B[src] + attr*wl)
        {
            int e = e0 + r;
            int dn = sdst[e], sn = ssrc[e];
            float at = sattr[e];
            if (q == 0) dst_s[r] = dn;
            const char* pa = (const char*)xab + (size_t)dn * 512 + q * 32;
            const char* pb = (const char*)xab + (size_t)sn * 512 + 256 + q * 32;
            short8 a0 = *(const short8*)pa, a1 = *(const short8*)(pa + 16);
            short8 b0 = *(const short8*)pb, b1x = *(const short8*)(pb + 16);
            short8 h0, h1;
#pragma unroll
            for (int i = 0; i < 8; i++) {
                h0[i] = bfb(sp_(b2f(a0[i]) + b2f(b0[i]) + at * wlv[i]));
                h1[i] = bfb(sp_(b2f(a1[i]) + b2f(b1x[i]) + at * wlv[8 + i]));
            }
            int swz = (r & 7) << 4;
            *(short8*)((char*)ht + r * 256 + ((q * 32) ^ swz)) = h0;
            *(short8*)((char*)ht + r * 256 + (((q * 32) + 16) ^ swz)) = h1;
        }
        __syncthreads();                       // A: ht + dst_s ready

        // ---- segment list (wave 0)
        if (wid == 0) {
            int d = dst_s[lane];
            int prev = (lane == 0) ? -1 : dst_s[lane - 1];
            bool start = (d != prev);
            unsigned long long mask = __ballot(start);
            int sidx = __popcll(mask & ((1ull << lane) - 1));
            if (start) { seg_start[sidx] = lane; seg_dst[sidx] = d; }
            if (lane == 63) {
                int ns = __popcll(mask);
                nseg_s = ns;
                seg_start[ns] = 64;
            }
        }

        // ---- GEMM2: [64x128] @ [128x128], wave owns 16 cols
        f32x4 acc2[4];
#pragma unroll
        for (int mi = 0; mi < 4; mi++) acc2[mi] = (f32x4){0.f, 0.f, 0.f, 0.f};
#pragma unroll
        for (int ks = 0; ks < 4; ks++) {
            int kb = ks * 64 + lk * 16;
            short8 av[4];
#pragma unroll
            for (int mi = 0; mi < 4; mi++) {
                int row = mi * 16 + lrow;
                av[mi] = *(const short8*)((const char*)ht + row * 256 + (kb ^ ((row & 7) << 4)));
            }
#pragma unroll
            for (int mi = 0; mi < 4; mi++)
                acc2[mi] = __builtin_amdgcn_mfma_f32_16x16x32_bf16(av[mi], w2f[ks], acc2[mi], 0, 0, 0);
        }
        // epilogue: softplus(+b2) -> f32 m-tile
#pragma unroll
        for (int mi = 0; mi < 4; mi++) {
#pragma unroll
            for (int rr = 0; rr < 4; rr++) {
                int row = mi * 16 + lk * 4 + rr;
                *(float*)((char*)mt + row * 512 + ((col * 4) ^ ((row & 7) << 4))) = sp_(acc2[mi][rr] + b2v);
            }
        }
        __syncthreads();                       // C: m-tile + seg list visible

        // ---- per-segment reduce + one atomicAdd per (segment, col)
        {
            int nseg = nseg_s;
            int rcol = t & 127, h = t >> 7;    // 4 thread-groups over segments
            for (int s = h; s < nseg; s += 4) {
                int r0 = seg_start[s], r1 = seg_start[s + 1];
                float sum = 0.f;
                for (int rr = r0; rr < r1; rr++)
                    sum += *(const float*)((const char*)mt + rr * 512 + ((rcol * 4) ^ ((rr & 7) << 4)));
                atomicAdd(&aggr[(size_t)seg_dst[s] * HID + rcol], sum);
            }
        }
        __syncthreads();                       // D: tile state reusable
    }
}

// ---------------------------------------------------------------- node MLP + BN partial stats
__launch_bounds__(256, 3)
__global__ void k_node(const __hip_bfloat16* __restrict__ xb,
                       const float* __restrict__ xf,
                       const float* __restrict__ aggr,
                       const short* __restrict__ w1T, const float* __restrict__ b1,
                       const short* __restrict__ w2T, const float* __restrict__ b2,
                       float* __restrict__ y, float* __restrict__ stats) {
    __shared__ short at[64 * 192];    // 24KB rowbytes 384
    __shared__ short ht[64 * 128];    // 16KB

    const int t = threadIdx.x;
    const int wid = t >> 6, lane = t & 63, lrow = lane & 15, lk = lane >> 4;
    const int n0 = blockIdx.x * 64;

    const int nc0 = wid * 32;
    short8 w1f[6][2];
    float b1v[2];
#pragma unroll
    for (int ni = 0; ni < 2; ni++) {
        int col = nc0 + ni * 16 + lrow;
#pragma unroll
        for (int ks = 0; ks < 6; ks++) {
            int kb = ks * 64 + lk * 16;
            w1f[ks][ni] = *(const short8*)((const char*)w1T + col * 384 + kb);
        }
        b1v[ni] = b1[col];
    }
    const int nc2 = wid * 16;
    const int col2 = nc2 + lrow;
    short8 w2f[4];
#pragma unroll
    for (int ks = 0; ks < 4; ks++)
        w2f[ks] = *(const short8*)((const char*)w2T + col2 * 256 + ks * 64 + lk * 16);
    const float b2v = b2[col2];

    if (t < 64) {
        int node = n0 + t;
        if (node < N_NODES) {
            const __hip_bfloat16* xr = xb + (size_t)node * DIM;
#pragma unroll
            for (int i = 0; i < 8; i++) {
                int4v v = *(const int4v*)(xr + i * 8);
                *(int4v*)((char*)at + t * 384 + ((i * 16) ^ ((t & 7) << 4))) = v;
            }
        } else {
            int4v z = {0, 0, 0, 0};
#pragma unroll
            for (int i = 0; i < 8; i++)
                *(int4v*)((char*)at + t * 384 + ((i * 16) ^ ((t & 7) << 4))) = z;
        }
    }
    {
        int r = t >> 2, q = t & 3;
        int node = n0 + r;
#pragma unroll
        for (int i = 0; i < 4; i++) {
            short8 s = {0, 0, 0, 0, 0, 0, 0, 0};
            if (node < N_NODES) {
                const float* ar = aggr + (size_t)node * HID + q * 32 + i * 8;
                float4 f0 = *(const float4*)ar;
                float4 f1 = *(const float4*)(ar + 4);
                s = (short8){bfb(f0.x), bfb(f0.y), bfb(f0.z), bfb(f0.w),
                             bfb(f1.x), bfb(f1.y), bfb(f1.z), bfb(f1.w)};
            }
            int cb = 128 + q * 64 + i * 16;
            *(short8*)((char*)at + r * 384 + (cb ^ ((r & 7) << 4))) = s;
        }
    }
    __syncthreads();

    f32x4 acc[4][2];
#pragma unroll
    for (int mi = 0; mi < 4; mi++)
#pragma unroll
        for (int ni = 0; ni < 2; ni++) acc[mi][ni] = (f32x4){0.f, 0.f, 0.f, 0.f};
#pragma unroll
    for (int ks = 0; ks < 6; ks++) {
        int kb = ks * 64 + lk * 16;
        short8 av[4];
#pragma unroll
        for (int mi = 0; mi < 4; mi++) {
            int row = mi * 16 + lrow;
            av[mi] = *(const short8*)((const char*)at + row * 384 + (kb ^ ((row & 7) << 4)));
        }
#pragma unroll
        for (int mi = 0; mi < 4; mi++)
#pragma unroll
            for (int ni = 0; ni < 2; ni++)
                acc[mi][ni] = __builtin_amdgcn_mfma_f32_16x16x32_bf16(av[mi], w1f[ks][ni], acc[mi][ni], 0, 0, 0);
    }
#pragma unroll
    for (int mi = 0; mi < 4; mi++) {
#pragma unroll
        for (int ni = 0; ni < 2; ni++) {
            int col = nc0 + ni * 16 + lrow;
#pragma unroll
            for (int rr = 0; rr < 4; rr++) {
                int row = mi * 16 + lk * 4 + rr;
                float val = sp_(acc[mi][ni][rr] + b1v[ni]);
                *(short*)((char*)ht + row * 256 + ((col * 2) ^ ((row & 7) << 4))) = bfb(val);
            }
        }
    }
    __syncthreads();

    f32x4 acc2[4];
#pragma unroll
    for (int mi = 0; mi < 4; mi++) acc2[mi] = (f32x4){0.f, 0.f, 0.f, 0.f};
#pragma unroll
    for (int ks = 0; ks < 4; ks++) {
        int kb = ks * 64 + lk * 16;
        short8 av[4];
#pragma unroll
        for (int mi = 0; mi < 4; mi++) {
            int row = mi * 16 + lrow;
            av[mi] = *(const short8*)((const char*)ht + row * 256 + (kb ^ ((row & 7) << 4)));
        }
#pragma unroll
        for (int mi = 0; mi < 4; mi++)
            acc2[mi] = __builtin_amdgcn_mfma_f32_16x16x32_bf16(av[mi], w2f[ks], acc2[mi], 0, 0, 0);
    }
    float s1 = 0.f, s2 = 0.f;
#pragma unroll
    for (int mi = 0; mi < 4; mi++) {
#pragma unroll
        for (int rr = 0; rr < 4; rr++) {
            int row = mi * 16 + lk * 4 + rr;
            int node = n0 + row;
            if (node < N_NODES) {
                float v = acc2[mi][rr] + b2v + xf[(size_t)node * DIM + col2];
                y[(size_t)node * DIM + col2] = v;
                s1 += v;
                s2 += v * v;
            }
        }
    }
    s1 += __shfl_xor(s1, 16); s1 += __shfl_xor(s1, 32);
    s2 += __shfl_xor(s2, 16); s2 += __shfl_xor(s2, 32);
    if (lane < 16) {
        atomicAdd(&stats[col2], s1);
        atomicAdd(&stats[64 + col2], s2);
    }
}

// ---------------------------------------------------------------- BN finalize
__global__ void k_bnfin(const float* __restrict__ gamma, const float* __restrict__ beta,
                        float* __restrict__ stats) {
    int d = threadIdx.x;
    float mu = stats[d] * (1.f / N_NODES);
    float var = stats[64 + d] * (1.f / N_NODES) - mu * mu;
    float rstd = rsqrtf(var + BN_EPS);
    float a = gamma[d] * rstd;
    stats[128 + d] = a;
    stats[192 + d] = beta[d] - mu * a;
}

// ---------------------------------------------------------------- BN apply -> new x (f32 + bf16)
__global__ void k_bnapply(const float* __restrict__ y, const float* __restrict__ stats,
                          float* __restrict__ x, __hip_bfloat16* __restrict__ xb) {
    int idx = (blockIdx.x * 256 + threadIdx.x) * 4;
    if (idx >= N_NODES * DIM) return;
    int d = idx & 63;
    float4 v = *(const float4*)(y + idx);
    float4 r;
    r.x = stats[128 + d + 0] * v.x + stats[192 + d + 0];
    r.y = stats[128 + d + 1] * v.y + stats[192 + d + 1];
    r.z = stats[128 + d + 2] * v.z + stats[192 + d + 2];
    r.w = stats[128 + d + 3] * v.w + stats[192 + d + 3];
    *(float4*)(x + idx) = r;
    short4v s = {bfb(r.x), bfb(r.y), bfb(r.z), bfb(r.w)};
    *(short4v*)((char*)(xb + idx)) = s;
}

// ---------------------------------------------------------------- pool: per-graph mean, no atomics
__global__ void k_pool2(const int* __restrict__ gstart, const float* __restrict__ x,
                        float* __restrict__ pooled) {
    __shared__ float red[256];
    const int g = blockIdx.x, t = threadIdx.x;
    const int d = t & 63, nl = t >> 6;
    const int s = gstart[g], e = gstart[g + 1];
    float sum = 0.f;
    for (int n = s + nl; n < e; n += 4)
        sum += x[(size_t)n * DIM + d];
    red[t] = sum;
    __syncthreads();
    if (t < 64) {
        float tot = red[t] + red[t + 64] + red[t + 128] + red[t + 192];
        int c = e - s;
        pooled[g * DIM + t] = tot / fmaxf((float)c, 1.f);
    }
}

// ---------------------------------------------------------------- output MLP (f32)
__global__ void k_out(const float* __restrict__ pooled,
                      const float* __restrict__ W1, const float* __restrict__ b1,
                      const float* __restrict__ W2, const float* __restrict__ b2,
                      float* __restrict__ out) {
    __shared__ float pl[64];
    __shared__ float wsum[2];
    int g = blockIdx.x, t = threadIdx.x;
    if (t < 64) pl[t] = pooled[g * 64 + t];
    __syncthreads();
    float a = b1[t];
#pragma unroll
    for (int d = 0; d < 64; d++) a += pl[d] * W1[d * 128 + t];
    float c = sp_(a) * W2[t];
#pragma unroll
    for (int off = 32; off >= 1; off >>= 1) c += __shfl_down(c, off);
    int lane = t & 63, wid = t >> 6;
    if (lane == 0) wsum[wid] = c;
    __syncthreads();
    if (t == 0) out[g] = wsum[0] + wsum[1] + b2[0];
}

// ---------------------------------------------------------------- launch
extern "C" void kernel_launch(void* const* d_in, const int* in_sizes, int n_in,
                              void* d_out, int out_size, void* d_ws, size_t ws_size,
                              hipStream_t stream) {
    const int*   az    = (const int*)d_in[0];
    const int*   ei    = (const int*)d_in[1];
    const float* eattr = (const float*)d_in[2];
    const int*   batch = (const int*)d_in[3];
    const float* emb   = (const float*)d_in[4];
    const float* eW1   = (const float*)d_in[5];
    const float* eb1   = (const float*)d_in[6];
    const float* eW2   = (const float*)d_in[7];
    const float* eb2   = (const float*)d_in[8];
    const float* nW1   = (const float*)d_in[9];
    const float* nb1   = (const float*)d_in[10];
    const float* nW2   = (const float*)d_in[11];
    const float* nb2   = (const float*)d_in[12];
    const float* gam   = (const float*)d_in[13];
    const float* bet   = (const float*)d_in[14];
    const float* oW1   = (const float*)d_in[15];
    const float* ob1   = (const float*)d_in[16];
    const float* oW2   = (const float*)d_in[17];
    const float* ob2   = (const float*)d_in[18];
    const int* esrc = ei;
    const int* edst = ei + N_EDGES;

    float* x     = (float*)d_ws;
    float* y     = x + (size_t)N_NODES * DIM;
    float* aggr  = y + (size_t)N_NODES * DIM;
    float* stats = aggr + (size_t)N_NODES * HID;     // 256 floats (adjacent: joint memset)
    float* pooled = stats + 256;                     // [128][64]
    __hip_bfloat16* xb = (__hip_bfloat16*)(pooled + NGRAPH * DIM);
    short* ew1T = (short*)(xb + (size_t)N_NODES * DIM);   // [3][128][128]
    short* ew2T = ew1T + 3 * 128 * 128;                   // [3][128][128]
    short* nw1T = ew2T + 3 * 128 * 128;                   // [3][128][192]
    short* nw2T = nw1T + 3 * 128 * 192;                   // [3][64][128]
    int*   cursor = (int*)(nw2T + 3 * 64 * 128);          // [50000]
    int*   ssrc   = cursor + N_NODES;                     // [800000]
    int*   sdstA  = ssrc + N_EDGES;                       // [800000]
    float* sattr  = (float*)(sdstA + N_EDGES);            // [800000]
    int*   gstart = (int*)(sattr + N_EDGES);              // [129]
    short* xab    = (short*)(gstart + 256);               // [50000][256] bf16

    k_embed<<<(N_NODES * DIM + 255) / 256, 256, 0, stream>>>(az, emb, x, xb);

    // pre-transpose all layer weights to bf16 [n][k]
    k_wprep<<<dim3(64, 3), 256, 0, stream>>>(eW1, ew1T, 128 * 128, 7, 129 * 128);
    k_wprep<<<dim3(64, 3), 256, 0, stream>>>(eW2, ew2T, 128 * 128, 7, 128 * 128);
    k_wprep<<<dim3(96, 3), 256, 0, stream>>>(nW1, nw1T, 192 * 128, 7, 192 * 128);
    k_wprep<<<dim3(32, 3), 256, 0, stream>>>(nW2, nw2T, 128 * 64, 6, 128 * 64);

    // counting sort of edges by dst (once per launch)
    hipMemsetAsync(cursor, 0, N_NODES * sizeof(int), stream);
    k_hist<<<(N_EDGES + 255) / 256, 256, 0, stream>>>(edst, cursor);
    k_scan<<<1, 1024, 0, stream>>>(cursor, cursor);   // in-place: per-thread own-index RMW
    k_scatter<<<(N_EDGES + 255) / 256, 256, 0, stream>>>(esrc, edst, eattr, cursor,
                                                         ssrc, sdstA, sattr);
    k_gbounds<<<1, 256, 0, stream>>>(batch, gstart);

    for (int l = 0; l < 3; l++) {
        hipMemsetAsync(aggr, 0, ((size_t)N_NODES * HID + 256) * sizeof(float), stream);
        k_ab<<<(N_NODES + 63) / 64, 512, 0, stream>>>(xb, ew1T + (size_t)l * 128 * 128,
                                                      eb1 + l * 128, xab);
        k_edge<<<500, 512, 0, stream>>>(xab, ssrc, sdstA, sattr,
                                        eW1 + (size_t)l * 129 * 128 + 128 * 128,
                                        eb2 + l * 128,
                                        ew2T + (size_t)l * 128 * 128,
                                        aggr);
        k_node<<<(N_NODES + 63) / 64, 256, 0, stream>>>(xb, x, aggr,
                                                        nw1T + (size_t)l * 128 * 192, nb1 + l * 128,
                                                        nw2T + (size_t)l * 64 * 128, nb2 + l * 64,
                                                        y, stats);
        k_bnfin<<<1, 64, 0, stream>>>(gam + l * 64, bet + l * 64, stats);
        k_bnapply<<<(N_NODES * DIM / 4 + 255) / 256, 256, 0, stream>>>(y, stats, x, xb);
    }

    k_pool2<<<NGRAPH, 256, 0, stream>>>(gstart, x, pooled);
    k_out<<<NGRAPH, 128, 0, stream>>>(pooled, oW1, ob1, oW2, ob2, (float*)d_out);
}

// Round 11
// 956.711 us; speedup vs baseline: 3.5552x; 1.0217x over previous
//
#include <hip/hip_runtime.h>
#include <hip/hip_bf16.h>

#define N_NODES 50000
#define N_EDGES 800000
#define DIM 64
#define HID 128
#define NGRAPH 128
#define BN_EPS 1e-5f

typedef __attribute__((ext_vector_type(8))) short short8;
typedef __attribute__((ext_vector_type(4))) short short4v;
typedef __attribute__((ext_vector_type(4))) float f32x4;
typedef __attribute__((ext_vector_type(4))) int int4v;

__device__ __forceinline__ float sp_(float v) {
    // softplus via hardware v_exp_f32 / v_log_f32 (~1e-6 abs err, fine at bf16)
    return fmaxf(v, 0.f) + __logf(1.f + __expf(-fabsf(v)));
}
__device__ __forceinline__ short bfb(float f) {
    __hip_bfloat16 h = __float2bfloat16(f);
    return __builtin_bit_cast(short, h);
}
__device__ __forceinline__ float b2f(short s) {
    unsigned u = ((unsigned)(unsigned short)s) << 16;
    return __builtin_bit_cast(float, u);
}

// ---------------------------------------------------------------- embed
__global__ void k_embed(const int* __restrict__ az, const float* __restrict__ emb,
                        float* __restrict__ x, __hip_bfloat16* __restrict__ xb) {
    int idx = blockIdx.x * 256 + threadIdx.x;
    if (idx >= N_NODES * DIM) return;
    int n = idx >> 6;
    int d = idx & 63;
    float v = emb[az[n] * DIM + d];
    x[idx] = v;
    xb[idx] = __float2bfloat16(v);
}

// ---------------------------------------------------------------- weight prep:
// transpose f32 [K][N] (row-major) -> bf16 [N][K]; blockIdx.y = layer
__global__ void k_wprep(const float* __restrict__ src, short* __restrict__ dst,
                        int total, int nshift, int srcStride) {
    int l = blockIdx.y;
    int idx = blockIdx.x * 256 + threadIdx.x;
    if (idx >= total) return;
    int K = total >> nshift;
    int k = idx >> nshift;
    int n = idx & ((1 << nshift) - 1);
    dst[(size_t)l * total + n * K + k] = bfb(src[(size_t)l * srcStride + idx]);
}

// ---------------------------------------------------------------- counting sort by dst
__global__ void k_hist(const int* __restrict__ edst, int* __restrict__ deg) {
    int e = blockIdx.x * 256 + threadIdx.x;
    if (e < N_EDGES) atomicAdd(&deg[edst[e]], 1);
}

// single block, 1024 threads: exclusive prefix sum deg -> cursor
__global__ void k_scan(const int* __restrict__ deg, int* __restrict__ cursor) {
    __shared__ int wsum[16];
    __shared__ int carry;
    const int t = threadIdx.x, lane = t & 63, w = t >> 6;
    if (t == 0) carry = 0;
    __syncthreads();
    for (int base = 0; base < N_NODES; base += 1024) {
        int i = base + t;
        int v = (i < N_NODES) ? deg[i] : 0;
        int s = v;
#pragma unroll
        for (int off = 1; off < 64; off <<= 1) {
            int u = __shfl_up(s, off);
            if (lane >= off) s += u;
        }
        if (lane == 63) wsum[w] = s;
        __syncthreads();
        if (w == 0) {
            int ws = (lane < 16) ? wsum[lane] : 0;
#pragma unroll
            for (int off = 1; off < 16; off <<= 1) {
                int u = __shfl_up(ws, off);
                if (lane >= off) ws += u;
            }
            if (lane < 16) wsum[lane] = ws;
        }
        __syncthreads();
        int woff = (w == 0) ? 0 : wsum[w - 1];
        int excl = carry + woff + s - v;
        if (i < N_NODES) cursor[i] = excl;
        __syncthreads();
        if (t == 1023) carry += wsum[15];
        __syncthreads();
    }
}

// scatter into interleaved edge records {src, dst, attr_bits, 0}
__global__ void k_scatter(const int* __restrict__ esrc, const int* __restrict__ edst,
                          const float* __restrict__ eattr, int* __restrict__ cursor,
                          int4v* __restrict__ sedge) {
    int e = blockIdx.x * 256 + threadIdx.x;
    if (e >= N_EDGES) return;
    int d = edst[e];
    int pos = atomicAdd(&cursor[d], 1);
    int4v rec = {esrc[e], d, __builtin_bit_cast(int, eattr[e]), 0};
    sedge[pos] = rec;
}

// ---------------------------------------------------------------- graph bounds
__global__ void k_gbounds(const int* __restrict__ batch, int* __restrict__ gstart) {
    int g = threadIdx.x;
    if (g > NGRAPH) return;
    int lo = 0, hi = N_NODES;
    while (lo < hi) {
        int mid = (lo + hi) >> 1;
        if (batch[mid] < g) lo = mid + 1; else hi = mid;
    }
    gstart[g] = lo;
}

// ---------------------------------------------------------------- per-node A/B:
// A[n] = x[n]@W1[0:64] + b1 (dst half), B[n] = x[n]@W1[64:128] (src half)
// output xab[n][0:128]=A bf16, [128:256]=B bf16
__launch_bounds__(512, 2)
__global__ void k_ab(const __hip_bfloat16* __restrict__ xb,
                     const short* __restrict__ w1T, const float* __restrict__ b1,
                     short* __restrict__ xab) {
    __shared__ short xt[64 * 64];     // 8KB, rowbytes 128
    __shared__ short ot[64 * 256];    // 32KB, rowbytes 512
    const int t = threadIdx.x;
    const int wid = t >> 6, lane = t & 63, lrow = lane & 15, lk = lane >> 4;
    const int col = wid * 16 + lrow;
    const int n0 = blockIdx.x * 64;

    short8 wa[2], wb[2];
#pragma unroll
    for (int ks = 0; ks < 2; ks++) {
        wa[ks] = *(const short8*)((const char*)w1T + col * 256 + ks * 64 + lk * 16);
        wb[ks] = *(const short8*)((const char*)w1T + col * 256 + 128 + ks * 64 + lk * 16);
    }
    const float b1v = b1[col];

    {   // stage x tile
        int r = t >> 3, q = t & 7;
        int node = n0 + r;
        int4v v = {0, 0, 0, 0};
        if (node < N_NODES) v = *(const int4v*)(xb + (size_t)node * DIM + q * 8);
        *(int4v*)((char*)xt + r * 128 + ((q * 16) ^ ((r & 7) << 4))) = v;
    }
    __syncthreads();

    f32x4 aa[4], ab[4];
#pragma unroll
    for (int mi = 0; mi < 4; mi++) { aa[mi] = (f32x4){0.f,0.f,0.f,0.f}; ab[mi] = (f32x4){0.f,0.f,0.f,0.f}; }
#pragma unroll
    for (int ks = 0; ks < 2; ks++) {
        int kb = ks * 64 + lk * 16;
        short8 av[4];
#pragma unroll
        for (int mi = 0; mi < 4; mi++) {
            int row = mi * 16 + lrow;
            av[mi] = *(const short8*)((const char*)xt + row * 128 + (kb ^ ((row & 7) << 4)));
        }
#pragma unroll
        for (int mi = 0; mi < 4; mi++) {
            aa[mi] = __builtin_amdgcn_mfma_f32_16x16x32_bf16(av[mi], wa[ks], aa[mi], 0, 0, 0);
            ab[mi] = __builtin_amdgcn_mfma_f32_16x16x32_bf16(av[mi], wb[ks], ab[mi], 0, 0, 0);
        }
    }
#pragma unroll
    for (int mi = 0; mi < 4; mi++) {
#pragma unroll
        for (int rr = 0; rr < 4; rr++) {
            int row = mi * 16 + lk * 4 + rr;
            int swz = (row & 7) << 4;
            *(short*)((char*)ot + row * 512 + ((col * 2) ^ swz)) = bfb(aa[mi][rr] + b1v);
            *(short*)((char*)ot + row * 512 + 256 + ((col * 2) ^ swz)) = bfb(ab[mi][rr]);
        }
    }
    __syncthreads();
    // coalesced LDS -> global copy (unswizzle)
#pragma unroll
    for (int it = 0; it < 4; it++) {
        int idx = it * 8192 + t * 16;
        int row = idx >> 9, off = idx & 511;
        int node = n0 + row;
        if (node < N_NODES) {
            int base = off & 256, lo = off & 255;
            int4v v = *(const int4v*)((char*)ot + row * 512 + base + (lo ^ ((row & 7) << 4)));
            *(int4v*)((char*)xab + (size_t)node * 512 + off) = v;
        }
    }
}

// ---------------------------------------------------------------- edge MLP (dst-sorted, A/B precomputed)
// 2 barriers/tile; next-tile gathers prefetched under the segment reduce.
__launch_bounds__(512, 4)
__global__ void k_edge(const short* __restrict__ xab,
                       const int4v* __restrict__ sedge,
                       const float* __restrict__ wl, const float* __restrict__ b2,
                       const short* __restrict__ w2T,
                       float* __restrict__ aggr) {
    __shared__ short ht[64 * 128];     // 16KB bf16 h-tile, rowbytes 256
    __shared__ float mt[64 * 128];     // 32KB f32 m-tile, rowbytes 512
    __shared__ int   dst_s[64];
    __shared__ int   seg_start[65];
    __shared__ int   seg_dst[64];
    __shared__ int   nseg_s;

    const int t = threadIdx.x;
    const int wid = t >> 6, lane = t & 63;
    const int lrow = lane & 15, lk = lane >> 4;
    const int r = t >> 3, q = t & 7;          // staging: 8 threads per edge row
    const int col = wid * 16 + lrow;          // GEMM output column

    short8 w2f[4];
#pragma unroll
    for (int ks = 0; ks < 4; ks++)
        w2f[ks] = *(const short8*)((const char*)w2T + col * 256 + ks * 64 + lk * 16);
    const float b2v = b2[col];
    float wlv[16];
#pragma unroll
    for (int i = 0; i < 16; i++) wlv[i] = wl[q * 16 + i];

    const int NT = N_EDGES / 64;              // 12500
    const int tile0 = (int)(((long)blockIdx.x * NT) / 1000);
    const int tile1 = (int)(((long)(blockIdx.x + 1) * NT) / 1000);

    // ---- prefetch state (tile t+1 loads issued under tile t's reduce)
    int4v ei;
    short8 ra0, ra1, rb0, rb1;
    {
        int e = tile0 * 64 + r;
        ei = sedge[e];
        const char* pa = (const char*)xab + (size_t)ei[1] * 512 + q * 32;
        const char* pb = (const char*)xab + (size_t)ei[0] * 512 + 256 + q * 32;
        ra0 = *(const short8*)pa;  ra1 = *(const short8*)(pa + 16);
        rb0 = *(const short8*)pb;  rb1 = *(const short8*)(pb + 16);
    }

    for (int tile = tile0; tile < tile1; ++tile) {
        // ---- stage h tile from prefetched regs: h = sp(A[dst]+B[src]+attr*wl)
        // safe pre-barrier: reduce(t-1) reads mt/seg_* only, never ht/dst_s
        {
            float at = __builtin_bit_cast(float, ei[2]);
            if (q == 0) dst_s[r] = ei[1];
            short8 h0, h1;
#pragma unroll
            for (int i = 0; i < 8; i++) {
                h0[i] = bfb(sp_(b2f(ra0[i]) + b2f(rb0[i]) + at * wlv[i]));
                h1[i] = bfb(sp_(b2f(ra1[i]) + b2f(rb1[i]) + at * wlv[8 + i]));
            }
            int swz = (r & 7) << 4;
            *(short8*)((char*)ht + r * 256 + ((q * 32) ^ swz)) = h0;
            *(short8*)((char*)ht + r * 256 + (((q * 32) + 16) ^ swz)) = h1;
        }
        __syncthreads();                       // A: ht + dst_s ready (and all waves
                                               //    done with previous reduce)

        // ---- segment list (wave 0)
        if (wid == 0) {
            int d = dst_s[lane];
            int prev = (lane == 0) ? -1 : dst_s[lane - 1];
            bool start = (d != prev);
            unsigned long long mask = __ballot(start);
            int sidx = __popcll(mask & ((1ull << lane) - 1));
            if (start) { seg_start[sidx] = lane; seg_dst[sidx] = d; }
            if (lane == 63) {
                int ns = __popcll(mask);
                nseg_s = ns;
                seg_start[ns] = 64;
            }
        }

        // ---- GEMM2: [64x128] @ [128x128], wave owns 16 cols
        f32x4 acc2[4];
#pragma unroll
        for (int mi = 0; mi < 4; mi++) acc2[mi] = (f32x4){0.f, 0.f, 0.f, 0.f};
#pragma unroll
        for (int ks = 0; ks < 4; ks++) {
            int kb = ks * 64 + lk * 16;
            short8 av[4];
#pragma unroll
            for (int mi = 0; mi < 4; mi++) {
                int row = mi * 16 + lrow;
                av[mi] = *(const short8*)((const char*)ht + row * 256 + (kb ^ ((row & 7) << 4)));
            }
#pragma unroll
            for (int mi = 0; mi < 4; mi++)
                acc2[mi] = __builtin_amdgcn_mfma_f32_16x16x32_bf16(av[mi], w2f[ks], acc2[mi], 0, 0, 0);
        }
        // epilogue: softplus(+b2) -> f32 m-tile
#pragma unroll
        for (int mi = 0; mi < 4; mi++) {
#pragma unroll
            for (int rr = 0; rr < 4; rr++) {
                int row = mi * 16 + lk * 4 + rr;
                *(float*)((char*)mt + row * 512 + ((col * 4) ^ ((row & 7) << 4))) = sp_(acc2[mi][rr] + b2v);
            }
        }
        __syncthreads();                       // C: m-tile + seg list visible

        // ---- prefetch next tile's gathers (latency hides under reduce)
        if (tile + 1 < tile1) {
            int e = (tile + 1) * 64 + r;
            ei = sedge[e];
            const char* pa = (const char*)xab + (size_t)ei[1] * 512 + q * 32;
            const char* pb = (const char*)xab + (size_t)ei[0] * 512 + 256 + q * 32;
            ra0 = *(const short8*)pa;  ra1 = *(const short8*)(pa + 16);
            rb0 = *(const short8*)pb;  rb1 = *(const short8*)(pb + 16);
        }

        // ---- per-segment reduce + one atomicAdd per (segment, col)
        {
            int nseg = nseg_s;
            int rcol = t & 127, h = t >> 7;    // 4 thread-groups over segments
            for (int s = h; s < nseg; s += 4) {
                int r0 = seg_start[s], r1 = seg_start[s + 1];
                float sum = 0.f;
                for (int rr = r0; rr < r1; rr++)
                    sum += *(const float*)((const char*)mt + rr * 512 + ((rcol * 4) ^ ((rr & 7) << 4)));
                atomicAdd(&aggr[(size_t)seg_dst[s] * HID + rcol], sum);
            }
        }
        // no barrier: next staging writes only ht/dst_s (not read by reduce);
        // barrier A fences seg_*/mt reuse collectively.
    }
}

// ---------------------------------------------------------------- node MLP + BN partial stats
__launch_bounds__(256, 3)
__global__ void k_node(const __hip_bfloat16* __restrict__ xb,
                       const float* __restrict__ xf,
                       const float* __restrict__ aggr,
                       const short* __restrict__ w1T, const float* __restrict__ b1,
                       const short* __restrict__ w2T, const float* __restrict__ b2,
                       float* __restrict__ y, float* __restrict__ stats) {
    __shared__ short at[64 * 192];    // 24KB rowbytes 384
    __shared__ short ht[64 * 128];    // 16KB

    const int t = threadIdx.x;
    const int wid = t >> 6, lane = t & 63, lrow = lane & 15, lk = lane >> 4;
    const int n0 = blockIdx.x * 64;

    const int nc0 = wid * 32;
    short8 w1f[6][2];
    float b1v[2];
#pragma unroll
    for (int ni = 0; ni < 2; ni++) {
        int col = nc0 + ni * 16 + lrow;
#pragma unroll
        for (int ks = 0; ks < 6; ks++) {
            int kb = ks * 64 + lk * 16;
            w1f[ks][ni] = *(const short8*)((const char*)w1T + col * 384 + kb);
        }
        b1v[ni] = b1[col];
    }
    const int nc2 = wid * 16;
    const int col2 = nc2 + lrow;
    short8 w2f[4];
#pragma unroll
    for (int ks = 0; ks < 4; ks++)
        w2f[ks] = *(const short8*)((const char*)w2T + col2 * 256 + ks * 64 + lk * 16);
    const float b2v = b2[col2];

    if (t < 64) {
        int node = n0 + t;
        if (node < N_NODES) {
            const __hip_bfloat16* xr = xb + (size_t)node * DIM;
#pragma unroll
            for (int i = 0; i < 8; i++) {
                int4v v = *(const int4v*)(xr + i * 8);
                *(int4v*)((char*)at + t * 384 + ((i * 16) ^ ((t & 7) << 4))) = v;
            }
        } else {
            int4v z = {0, 0, 0, 0};
#pragma unroll
            for (int i = 0; i < 8; i++)
                *(int4v*)((char*)at + t * 384 + ((i * 16) ^ ((t & 7) << 4))) = z;
        }
    }
    {
        int r = t >> 2, q = t & 3;
        int node = n0 + r;
#pragma unroll
        for (int i = 0; i < 4; i++) {
            short8 s = {0, 0, 0, 0, 0, 0, 0, 0};
            if (node < N_NODES) {
                const float* ar = aggr + (size_t)node * HID + q * 32 + i * 8;
                float4 f0 = *(const float4*)ar;
                float4 f1 = *(const float4*)(ar + 4);
                s = (short8){bfb(f0.x), bfb(f0.y), bfb(f0.z), bfb(f0.w),
                             bfb(f1.x), bfb(f1.y), bfb(f1.z), bfb(f1.w)};
            }
            int cb = 128 + q * 64 + i * 16;
            *(short8*)((char*)at + r * 384 + (cb ^ ((r & 7) << 4))) = s;
        }
    }
    __syncthreads();

    f32x4 acc[4][2];
#pragma unroll
    for (int mi = 0; mi < 4; mi++)
#pragma unroll
        for (int ni = 0; ni < 2; ni++) acc[mi][ni] = (f32x4){0.f, 0.f, 0.f, 0.f};
#pragma unroll
    for (int ks = 0; ks < 6; ks++) {
        int kb = ks * 64 + lk * 16;
        short8 av[4];
#pragma unroll
        for (int mi = 0; mi < 4; mi++) {
            int row = mi * 16 + lrow;
            av[mi] = *(const short8*)((const char*)at + row * 384 + (kb ^ ((row & 7) << 4)));
        }
#pragma unroll
        for (int mi = 0; mi < 4; mi++)
#pragma unroll
            for (int ni = 0; ni < 2; ni++)
                acc[mi][ni] = __builtin_amdgcn_mfma_f32_16x16x32_bf16(av[mi], w1f[ks][ni], acc[mi][ni], 0, 0, 0);
    }
#pragma unroll
    for (int mi = 0; mi < 4; mi++) {
#pragma unroll
        for (int ni = 0; ni < 2; ni++) {
            int col = nc0 + ni * 16 + lrow;
#pragma unroll
            for (int rr = 0; rr < 4; rr++) {
                int row = mi * 16 + lk * 4 + rr;
                float val = sp_(acc[mi][ni][rr] + b1v[ni]);
                *(short*)((char*)ht + row * 256 + ((col * 2) ^ ((row & 7) << 4))) = bfb(val);
            }
        }
    }
    __syncthreads();

    f32x4 acc2[4];
#pragma unroll
    for (int mi = 0; mi < 4; mi++) acc2[mi] = (f32x4){0.f, 0.f, 0.f, 0.f};
#pragma unroll
    for (int ks = 0; ks < 4; ks++) {
        int kb = ks * 64 + lk * 16;
        short8 av[4];
#pragma unroll
        for (int mi = 0; mi < 4; mi++) {
            int row = mi * 16 + lrow;
            av[mi] = *(const short8*)((const char*)ht + row * 256 + (kb ^ ((row & 7) << 4)));
        }
#pragma unroll
        for (int mi = 0; mi < 4; mi++)
            acc2[mi] = __builtin_amdgcn_mfma_f32_16x16x32_bf16(av[mi], w2f[ks], acc2[mi], 0, 0, 0);
    }
    float s1 = 0.f, s2 = 0.f;
#pragma unroll
    for (int mi = 0; mi < 4; mi++) {
#pragma unroll
        for (int rr = 0; rr < 4; rr++) {
            int row = mi * 16 + lk * 4 + rr;
            int node = n0 + row;
            if (node < N_NODES) {
                float v = acc2[mi][rr] + b2v + xf[(size_t)node * DIM + col2];
                y[(size_t)node * DIM + col2] = v;
                s1 += v;
                s2 += v * v;
            }
        }
    }
    s1 += __shfl_xor(s1, 16); s1 += __shfl_xor(s1, 32);
    s2 += __shfl_xor(s2, 16); s2 += __shfl_xor(s2, 32);
    if (lane < 16) {
        atomicAdd(&stats[col2], s1);
        atomicAdd(&stats[64 + col2], s2);
    }
}

// ---------------------------------------------------------------- BN finalize
__global__ void k_bnfin(const float* __restrict__ gamma, const float* __restrict__ beta,
                        float* __restrict__ stats) {
    int d = threadIdx.x;
    float mu = stats[d] * (1.f / N_NODES);
    float var = stats[64 + d] * (1.f / N_NODES) - mu * mu;
    float rstd = rsqrtf(var + BN_EPS);
    float a = gamma[d] * rstd;
    stats[128 + d] = a;
    stats[192 + d] = beta[d] - mu * a;
}

// ---------------------------------------------------------------- BN apply -> new x (f32 + bf16)
__global__ void k_bnapply(const float* __restrict__ y, const float* __restrict__ stats,
                          float* __restrict__ x, __hip_bfloat16* __restrict__ xb) {
    int idx = (blockIdx.x * 256 + threadIdx.x) * 4;
    if (idx >= N_NODES * DIM) return;
    int d = idx & 63;
    float4 v = *(const float4*)(y + idx);
    float4 r;
    r.x = stats[128 + d + 0] * v.x + stats[192 + d + 0];
    r.y = stats[128 + d + 1] * v.y + stats[192 + d + 1];
    r.z = stats[128 + d + 2] * v.z + stats[192 + d + 2];
    r.w = stats[128 + d + 3] * v.w + stats[192 + d + 3];
    *(float4*)(x + idx) = r;
    short4v s = {bfb(r.x), bfb(r.y), bfb(r.z), bfb(r.w)};
    *(short4v*)((char*)(xb + idx)) = s;
}

// ---------------------------------------------------------------- pool: per-graph mean, no atomics
__global__ void k_pool2(const int* __restrict__ gstart, const float* __restrict__ x,
                        float* __restrict__ pooled) {
    __shared__ float red[256];
    const int g = blockIdx.x, t = threadIdx.x;
    const int d = t & 63, nl = t >> 6;
    const int s = gstart[g], e = gstart[g + 1];
    float sum = 0.f;
    for (int n = s + nl; n < e; n += 4)
        sum += x[(size_t)n * DIM + d];
    red[t] = sum;
    __syncthreads();
    if (t < 64) {
        float tot = red[t] + red[t + 64] + red[t + 128] + red[t + 192];
        int c = e - s;
        pooled[g * DIM + t] = tot / fmaxf((float)c, 1.f);
    }
}

// ---------------------------------------------------------------- output MLP (f32)
__global__ void k_out(const float* __restrict__ pooled,
                      const float* __restrict__ W1, const float* __restrict__ b1,
                      const float* __restrict__ W2, const float* __restrict__ b2,
                      float* __restrict__ out) {
    __shared__ float pl[64];
    __shared__ float wsum[2];
    int g = blockIdx.x, t = threadIdx.x;
    if (t < 64) pl[t] = pooled[g * 64 + t];
    __syncthreads();
    float a = b1[t];
#pragma unroll
    for (int d = 0; d < 64; d++) a += pl[d] * W1[d * 128 + t];
    float c = sp_(a) * W2[t];
#pragma unroll
    for (int off = 32; off >= 1; off >>= 1) c += __shfl_down(c, off);
    int lane = t & 63, wid = t >> 6;
    if (lane == 0) wsum[wid] = c;
    __syncthreads();
    if (t == 0) out[g] = wsum[0] + wsum[1] + b2[0];
}

// ---------------------------------------------------------------- launch
extern "C" void kernel_launch(void* const* d_in, const int* in_sizes, int n_in,
                              void* d_out, int out_size, void* d_ws, size_t ws_size,
                              hipStream_t stream) {
    const int*   az    = (const int*)d_in[0];
    const int*   ei    = (const int*)d_in[1];
    const float* eattr = (const float*)d_in[2];
    const int*   batch = (const int*)d_in[3];
    const float* emb   = (const float*)d_in[4];
    const float* eW1   = (const float*)d_in[5];
    const float* eb1   = (const float*)d_in[6];
    const float* eW2   = (const float*)d_in[7];
    const float* eb2   = (const float*)d_in[8];
    const float* nW1   = (const float*)d_in[9];
    const float* nb1   = (const float*)d_in[10];
    const float* nW2   = (const float*)d_in[11];
    const float* nb2   = (const float*)d_in[12];
    const float* gam   = (const float*)d_in[13];
    const float* bet   = (const float*)d_in[14];
    const float* oW1   = (const float*)d_in[15];
    const float* ob1   = (const float*)d_in[16];
    const float* oW2   = (const float*)d_in[17];
    const float* ob2   = (const float*)d_in[18];
    const int* esrc = ei;
    const int* edst = ei + N_EDGES;

    float* x     = (float*)d_ws;
    float* y     = x + (size_t)N_NODES * DIM;
    float* aggr  = y + (size_t)N_NODES * DIM;
    float* stats = aggr + (size_t)N_NODES * HID;     // 256 floats (adjacent: joint memset)
    float* pooled = stats + 256;                     // [128][64]
    __hip_bfloat16* xb = (__hip_bfloat16*)(pooled + NGRAPH * DIM);
    short* ew1T = (short*)(xb + (size_t)N_NODES * DIM);   // [3][128][128]
    short* ew2T = ew1T + 3 * 128 * 128;                   // [3][128][128]
    short* nw1T = ew2T + 3 * 128 * 128;                   // [3][128][192]
    short* nw2T = nw1T + 3 * 128 * 192;                   // [3][64][128]
    int*   cursor = (int*)(nw2T + 3 * 64 * 128);          // [50000]
    int4v* sedge  = (int4v*)(cursor + N_NODES + 48);      // [800000] 16B recs (align)
    int*   gstart = (int*)(sedge + N_EDGES);              // [129]
    short* xab    = (short*)(gstart + 256);               // [50000][256] bf16

    k_embed<<<(N_NODES * DIM + 255) / 256, 256, 0, stream>>>(az, emb, x, xb);

    // pre-transpose all layer weights to bf16 [n][k]
    k_wprep<<<dim3(64, 3), 256, 0, stream>>>(eW1, ew1T, 128 * 128, 7, 129 * 128);
    k_wprep<<<dim3(64, 3), 256, 0, stream>>>(eW2, ew2T, 128 * 128, 7, 128 * 128);
    k_wprep<<<dim3(96, 3), 256, 0, stream>>>(nW1, nw1T, 192 * 128, 7, 192 * 128);
    k_wprep<<<dim3(32, 3), 256, 0, stream>>>(nW2, nw2T, 128 * 64, 6, 128 * 64);

    // counting sort of edges by dst (once per launch)
    hipMemsetAsync(cursor, 0, N_NODES * sizeof(int), stream);
    k_hist<<<(N_EDGES + 255) / 256, 256, 0, stream>>>(edst, cursor);
    k_scan<<<1, 1024, 0, stream>>>(cursor, cursor);   // in-place: per-thread own-index RMW
    k_scatter<<<(N_EDGES + 255) / 256, 256, 0, stream>>>(esrc, edst, eattr, cursor, sedge);
    k_gbounds<<<1, 256, 0, stream>>>(batch, gstart);

    for (int l = 0; l < 3; l++) {
        hipMemsetAsync(aggr, 0, ((size_t)N_NODES * HID + 256) * sizeof(float), stream);
        k_ab<<<(N_NODES + 63) / 64, 512, 0, stream>>>(xb, ew1T + (size_t)l * 128 * 128,
                                                      eb1 + l * 128, xab);
        k_edge<<<1000, 512, 0, stream>>>(xab, sedge,
                                         eW1 + (size_t)l * 129 * 128 + 128 * 128,
                                         eb2 + l * 128,
                                         ew2T + (size_t)l * 128 * 128,
                                         aggr);
        k_node<<<(N_NODES + 63) / 64, 256, 0, stream>>>(xb, x, aggr,
                                                        nw1T + (size_t)l * 128 * 192, nb1 + l * 128,
                                                        nw2T + (size_t)l * 64 * 128, nb2 + l * 64,
                                                        y, stats);
        k_bnfin<<<1, 64, 0, stream>>>(gam + l * 64, bet + l * 64, stats);
        k_bnapply<<<(N_NODES * DIM / 4 + 255) / 256, 256, 0, stream>>>(y, stats, x, xb);
    }

    k_pool2<<<NGRAPH, 256, 0, stream>>>(gstart, x, pooled);
    k_out<<<NGRAPH, 128, 0, stream>>>(pooled, oW1, ob1, oW2, ob2, (float*)d_out);
}